// Round 6
// baseline (400.887 us; speedup 1.0000x reference)
//
#include <hip/hip_runtime.h>
#include <stdint.h>

// SoftmaxAttention: x[2,2048,2048] f32, w_qkv[6144,2048] f32, w_out[2048,2048] f32
// out[2,2048,2048] f32.  All matmul-shaped compute via bf16 MFMA 16x16x32.

typedef __attribute__((ext_vector_type(8))) short bf16x8;
typedef __attribute__((ext_vector_type(8))) unsigned short u16x8;
typedef __attribute__((ext_vector_type(4))) unsigned short u16x4;
typedef __attribute__((ext_vector_type(4))) float f32x4;

#define MFMA16(a, b, c) __builtin_amdgcn_mfma_f32_16x16x32_bf16((a), (b), (c), 0, 0, 0)

__device__ __forceinline__ unsigned short f2bf(float f) {
  union { float f; uint32_t u; } v; v.f = f;
  uint32_t r = v.u + 0x7FFFu + ((v.u >> 16) & 1u);  // RNE
  return (unsigned short)(r >> 16);
}

__device__ __forceinline__ void gld_lds16(const unsigned short* g, unsigned short* lds) {
  __builtin_amdgcn_global_load_lds(
      (const __attribute__((address_space(1))) void*)g,
      (__attribute__((address_space(3))) void*)lds, 16, 0, 0);
}

// ---------------------------------------------------------------- cvt f32->bf16
__global__ __launch_bounds__(256) void cvt_bf16(const float* __restrict__ in,
                                                unsigned short* __restrict__ out, int n8) {
  int stride = gridDim.x * blockDim.x;
  for (int i = blockIdx.x * blockDim.x + threadIdx.x; i < n8; i += stride) {
    float4 a = reinterpret_cast<const float4*>(in)[i * 2];
    float4 b = reinterpret_cast<const float4*>(in)[i * 2 + 1];
    u16x8 o;
    o[0] = f2bf(a.x); o[1] = f2bf(a.y); o[2] = f2bf(a.z); o[3] = f2bf(a.w);
    o[4] = f2bf(b.x); o[5] = f2bf(b.y); o[6] = f2bf(b.z); o[7] = f2bf(b.w);
    reinterpret_cast<u16x8*>(out)[i] = o;
  }
}

// ================ 128x128 bf16 GEMM core, dbuf 2-phase, peeled (B^T) ==========
// C[m][n] = sum_k A[m][k]*Bt[n][k].  256 thr, 4 waves (2x2 of 64x64).  BK=32.
// Granule swizzle (tid&3)^((row>>1)&3) both sides (rule #21): 0 conflicts.
#define STG128(BUFOFF, KOFF)                                                    \
  do {                                                                          \
    gld_lds16(gA0 + (KOFF), ldsA + (BUFOFF) + tid * 8);                         \
    gld_lds16(gA1 + (KOFF), ldsA + (BUFOFF) + 2048 + tid * 8);                  \
    gld_lds16(gB0 + (KOFF), ldsB + (BUFOFF) + tid * 8);                         \
    gld_lds16(gB1 + (KOFF), ldsB + (BUFOFF) + 2048 + tid * 8);                  \
  } while (0)

__device__ __forceinline__ void gemm128_step(const unsigned short* la,
                                             const unsigned short* lb,
                                             int wr, int wc, int fm, int fswz8,
                                             f32x4 acc[4][4]) {
  bf16x8 af[4], bfv[4];
#pragma unroll
  for (int i = 0; i < 4; i++)
    af[i] = *(const bf16x8*)&la[(wr + i * 16 + fm) * 32 + fswz8];
#pragma unroll
  for (int j = 0; j < 4; j++)
    bfv[j] = *(const bf16x8*)&lb[(wc + j * 16 + fm) * 32 + fswz8];
#pragma unroll
  for (int i = 0; i < 4; i++)
#pragma unroll
    for (int j = 0; j < 4; j++)
      acc[i][j] = MFMA16(af[i], bfv[j], acc[i][j]);
}

__device__ __forceinline__ void gemm128_dbuf(const unsigned short* __restrict__ A,
                                             const unsigned short* __restrict__ Bt,
                                             int K, int brow, int bcol,
                                             unsigned short* ldsA, unsigned short* ldsB,
                                             f32x4 acc[4][4]) {
  const int tid = threadIdx.x;
  const int l = tid & 63;
  const int w = tid >> 6;
  const int wr = (w >> 1) << 6;
  const int wc = (w & 1) << 6;

  const int srow = tid >> 2;                       // staging row within 64-row chunk
  const int sswz = (tid & 3) ^ ((srow >> 1) & 3);  // swizzled 16B granule
  const unsigned short* gA0 = A + (size_t)(brow + srow) * K + 8 * sswz;
  const unsigned short* gA1 = gA0 + (size_t)64 * K;
  const unsigned short* gB0 = Bt + (size_t)(bcol + srow) * K + 8 * sswz;
  const unsigned short* gB1 = gB0 + (size_t)64 * K;

  const int fm = l & 15;
  const int fswz8 = 8 * ((l >> 4) ^ ((fm >> 1) & 3));

  STG128(0, 0);
  __syncthreads();  // drains vmcnt(0)

  for (int k0 = 0; k0 < K - 64; k0 += 64) {
    STG128(4096, k0 + 32);
    gemm128_step(ldsA, ldsB, wr, wc, fm, fswz8, acc);
    __syncthreads();
    STG128(0, k0 + 64);
    gemm128_step(ldsA + 4096, ldsB + 4096, wr, wc, fm, fswz8, acc);
    __syncthreads();
  }
  // tail: k0 = K-64
  STG128(4096, K - 32);
  gemm128_step(ldsA, ldsB, wr, wc, fm, fswz8, acc);
  __syncthreads();
  gemm128_step(ldsA + 4096, ldsB + 4096, wr, wc, fm, fswz8, acc);
}

// --------------------------------------------------------------- QKV projection
// grid 1536 flat; T1 XCD chunking: xcd = bid&7 owns bx in [xcd*6, xcd*6+6).
__global__ __launch_bounds__(256) void gemm_qkv(const unsigned short* __restrict__ xb,
                                                const unsigned short* __restrict__ wqb,
                                                unsigned short* __restrict__ Qb,
                                                unsigned short* __restrict__ Kb,
                                                unsigned short* __restrict__ Vtb) {
  __shared__ alignas(16) unsigned short ldsA[2 * 128 * 32];
  __shared__ alignas(16) unsigned short ldsB[2 * 128 * 32];
  f32x4 acc[4][4];
#pragma unroll
  for (int i = 0; i < 4; i++)
#pragma unroll
    for (int j = 0; j < 4; j++) acc[i][j] = (f32x4){0.f, 0.f, 0.f, 0.f};

  const int bid = blockIdx.x;
  const int xcd = bid & 7;
  const int loc = bid >> 3;              // 0..191
  const int bx = xcd * 6 + loc % 6;      // 0..47
  const int by = loc / 6;                // 0..31
  const int brow = by << 7;
  const int bcol = bx << 7;

  gemm128_dbuf(xb, wqb, 2048, brow, bcol, ldsA, ldsB, acc);

  const int l = threadIdx.x & 63;
  const int w = threadIdx.x >> 6;
  const int wr = (w >> 1) << 6, wc = (w & 1) << 6;
  const int which = bcol >> 11;                         // 0=Q 1=K 2=V (block-uniform)
  const int bh = ((brow >> 11) << 4) | ((bcol >> 7) & 15);
  const int tbase = (brow & 2047) + wr + ((l >> 4) << 2);

#pragma unroll
  for (int i = 0; i < 4; i++) {
    const int t0 = tbase + i * 16;
#pragma unroll
    for (int j = 0; j < 4; j++) {
      const int d = wc + j * 16 + (l & 15);
      if (which == 2) {
        u16x4 pk;
#pragma unroll
        for (int r = 0; r < 4; r++) pk[r] = f2bf(acc[i][j][r]);
        *reinterpret_cast<u16x4*>(&Vtb[((size_t)bh * 128 + d) * 2048 + t0]) = pk;
      } else {
        unsigned short* dst = (which == 0 ? Qb : Kb) + ((size_t)bh * 2048 + t0) * 128 + d;
#pragma unroll
        for (int r = 0; r < 4; r++) dst[(size_t)r * 128] = f2bf(acc[i][j][r]);
      }
    }
  }
}

// -------------------------------------------------------------- output projection
__global__ __launch_bounds__(256) void gemm_out(const unsigned short* __restrict__ yb,
                                                const unsigned short* __restrict__ wob,
                                                float* __restrict__ out) {
  __shared__ alignas(16) unsigned short ldsA[2 * 128 * 32];
  __shared__ alignas(16) unsigned short ldsB[2 * 128 * 32];
  f32x4 acc[4][4];
#pragma unroll
  for (int i = 0; i < 4; i++)
#pragma unroll
    for (int j = 0; j < 4; j++) acc[i][j] = (f32x4){0.f, 0.f, 0.f, 0.f};

  const int bid = blockIdx.x;
  const int xcd = bid & 7;
  const int loc = bid >> 3;                       // 0..63
  const int bx = (xcd & 3) * 4 + (loc & 3);       // 0..15
  const int by = (xcd >> 2) * 16 + (loc >> 2);    // 0..31
  const int brow = by << 7;
  const int bcol = bx << 7;

  gemm128_dbuf(yb, wob, 2048, brow, bcol, ldsA, ldsB, acc);

  const int l = threadIdx.x & 63;
  const int w = threadIdx.x >> 6;
  const int wr = (w >> 1) << 6, wc = (w & 1) << 6;
#pragma unroll
  for (int i = 0; i < 4; i++) {
    const int m0 = brow + wr + i * 16 + ((l >> 4) << 2);
#pragma unroll
    for (int j = 0; j < 4; j++) {
      const int n = bcol + wc + j * 16 + (l & 15);
#pragma unroll
      for (int r = 0; r < 4; r++) out[(size_t)(m0 + r) * 2048 + n] = acc[i][j][r];
    }
  }
}

// ------------------------------------------------------------------ flash attn
// PAIRED causal tiles (j, 31-j) => 33 kv-steps/block, perfect balance.
// K double-buffered in LDS (stage t+1 before compute t; ONE barrier/step);
// V read DIRECT from global (XCD-grouped KV -> L2-resident; drops V staging,
// halves LDS read traffic).  LDS 40 KiB (K 2x16 + P 8) -> 4 blocks/CU.
__device__ __forceinline__ void stage_k64(const unsigned short* __restrict__ Kg,
                                          int kv0, unsigned short* dst, int tid) {
#pragma unroll
  for (int c = 0; c < 4; c++) {
    int s = c * 256 + tid;
    int row = s >> 4, g = s & 15;
    gld_lds16(&Kg[(size_t)(kv0 + row) * 128 + 8 * (g ^ (row & 7))], &dst[s * 8]);
  }
}

__global__ __launch_bounds__(256) void attn_kernel(const unsigned short* __restrict__ Qb,
                                                   const unsigned short* __restrict__ Kb,
                                                   const unsigned short* __restrict__ Vtb,
                                                   unsigned short* __restrict__ Yb) {
  __shared__ alignas(16) unsigned short lds_k[2][64 * 128];
  __shared__ alignas(16) unsigned short p_lds[4][16 * 64];

  const int tid = threadIdx.x;
  const int l = tid & 63;
  const int w = tid >> 6;

  const int bid = blockIdx.x;                // 0..511
  const int xcd = bid & 7;
  const int loc = bid >> 3;                  // 0..63
  const int bh = xcd * 4 + (loc >> 4);       // 0..31
  const int jidx = loc & 15;                 // 0..15

  const int b = bh >> 4, h = bh & 15;
  const float SC = 0.12752585f;  // log2(e)/sqrt(128)

  const unsigned short* Qg = Qb + (size_t)bh * 2048 * 128;
  const unsigned short* Kg = Kb + (size_t)bh * 2048 * 128;
  const unsigned short* Vg = Vtb + (size_t)bh * 128 * 2048;

  for (int ph = 0; ph < 2; ph++) {
    const int h64 = (ph == 0) ? jidx : (31 - jidx);
    const int q0 = h64 << 6;
    const int qw0 = q0 + (w << 4);

    // Q fragments in registers (A-operand: m = l&15, k = ds*32 + 8*(l>>4))
    bf16x8 qf[4];
#pragma unroll
    for (int ds = 0; ds < 4; ds++)
      qf[ds] = *(const bf16x8*)&Qg[(size_t)(qw0 + (l & 15)) * 128 + ds * 32 + 8 * (l >> 4)];

    f32x4 yacc[8];
#pragma unroll
    for (int dt = 0; dt < 8; dt++) yacc[dt] = (f32x4){0.f, 0.f, 0.f, 0.f};
    float mrow[4], lrow[4];
#pragma unroll
    for (int r = 0; r < 4; r++) { mrow[r] = -1e30f; lrow[r] = 0.f; }

    const int nkv = h64 + 1;

    // prologue: stage K tile 0
    stage_k64(Kg, 0, lds_k[0], tid);
    asm volatile("s_waitcnt vmcnt(0)" ::: "memory");
    __syncthreads();

    for (int t = 0; t < nkv; t++) {
      const int kv0 = t << 6;
      const unsigned short* kb = lds_k[t & 1];
      if (t + 1 < nkv) stage_k64(Kg, kv0 + 64, lds_k[(t & 1) ^ 1], tid);

      if (kv0 <= qw0 + 15) {  // wave has at least one unmasked row
        // S = Q K^T : 16 MFMA
        f32x4 sfr[4];
#pragma unroll
        for (int kt = 0; kt < 4; kt++) {
          const int kr = kt * 16 + (l & 15);
          f32x4 s4 = (f32x4){0.f, 0.f, 0.f, 0.f};
#pragma unroll
          for (int ds = 0; ds < 4; ds++) {
            bf16x8 kfr = *(const bf16x8*)&kb[kr * 128 + 8 * (((ds << 2) + (l >> 4)) ^ (kr & 7))];
            s4 = MFMA16(qf[ds], kfr, s4);
          }
          sfr[kt] = s4;
        }
        const bool need_mask = (kv0 + 63 > qw0);
#pragma unroll
        for (int kt = 0; kt < 4; kt++)
#pragma unroll
          for (int r = 0; r < 4; r++) {
            float sv = sfr[kt][r] * SC;
            if (need_mask) {
              int qa = qw0 + ((l >> 4) << 2) + r;
              int ka = kv0 + kt * 16 + (l & 15);
              sv = (ka > qa) ? -1e30f : sv;
            }
            sfr[kt][r] = sv;
          }
        // online softmax (log2 domain); rows at (l>>4)*4 + r, cols on l&15
        float rmax, f[4], rsum[4];
#pragma unroll
        for (int r = 0; r < 4; r++) {
          rmax = fmaxf(fmaxf(sfr[0][r], sfr[1][r]), fmaxf(sfr[2][r], sfr[3][r]));
          rmax = fmaxf(rmax, __shfl_xor(rmax, 1));
          rmax = fmaxf(rmax, __shfl_xor(rmax, 2));
          rmax = fmaxf(rmax, __shfl_xor(rmax, 4));
          rmax = fmaxf(rmax, __shfl_xor(rmax, 8));
          float mn = fmaxf(mrow[r], rmax);
          f[r] = exp2f(mrow[r] - mn);
          mrow[r] = mn;
          rsum[r] = 0.f;
        }
        // P = exp2(S - m), stash bf16 into per-wave swizzled LDS
#pragma unroll
        for (int kt = 0; kt < 4; kt++)
#pragma unroll
          for (int r = 0; r < 4; r++) {
            float p = exp2f(sfr[kt][r] - mrow[r]);
            rsum[r] += p;
            int row = ((l >> 4) << 2) + r;
            int k = kt * 16 + (l & 15);
            p_lds[w][row * 64 + (((k >> 3) ^ (row & 7)) << 3) + (k & 7)] = f2bf(p);
          }
#pragma unroll
        for (int r = 0; r < 4; r++) {
          float s = rsum[r];
          s += __shfl_xor(s, 1);
          s += __shfl_xor(s, 2);
          s += __shfl_xor(s, 4);
          s += __shfl_xor(s, 8);
          lrow[r] = lrow[r] * f[r] + s;
        }
#pragma unroll
        for (int dt = 0; dt < 8; dt++)
#pragma unroll
          for (int r = 0; r < 4; r++) yacc[dt][r] *= f[r];

        // cross-lane LDS write->read fence (same wave)
        asm volatile("s_waitcnt lgkmcnt(0)" ::: "memory");
        __builtin_amdgcn_sched_barrier(0);

        // PV: V^T fragments loaded DIRECT from global (L2-resident)
#pragma unroll
        for (int ks = 0; ks < 2; ks++) {
          bf16x8 vbr[8];
#pragma unroll
          for (int dt = 0; dt < 8; dt++)
            vbr[dt] = *(const bf16x8*)&Vg[(size_t)(dt * 16 + (l & 15)) * 2048 +
                                          kv0 + ks * 32 + 8 * (l >> 4)];
          const int prow = l & 15;
          bf16x8 pa = *(const bf16x8*)&p_lds[w][prow * 64 + ((((ks << 2) + (l >> 4)) ^ (prow & 7)) << 3)];
#pragma unroll
          for (int dt = 0; dt < 8; dt++)
            yacc[dt] = MFMA16(pa, vbr[dt], yacc[dt]);
        }
      }
      // one wait+barrier per step: K(t+1) staged, everyone done with kb
      asm volatile("s_waitcnt vmcnt(0)" ::: "memory");
      __syncthreads();
    }
    // epilogue: y = acc / l, bf16 into [B,T,C] (C index = h*128 + d)
#pragma unroll
    for (int dt = 0; dt < 8; dt++)
#pragma unroll
      for (int r = 0; r < 4; r++) {
        int qa = qw0 + ((l >> 4) << 2) + r;
        Yb[((size_t)(b * 2048 + qa)) * 2048 + h * 128 + dt * 16 + (l & 15)] =
            f2bf(yacc[dt][r] / lrow[r]);
      }
  }
}

// ---------------------------------------------------------------------- launch
extern "C" void kernel_launch(void* const* d_in, const int* in_sizes, int n_in,
                              void* d_out, int out_size, void* d_ws, size_t ws_size,
                              hipStream_t stream) {
  const float* x    = (const float*)d_in[0];
  const float* wqkv = (const float*)d_in[1];
  const float* wout = (const float*)d_in[2];
  float* out = (float*)d_out;

  // workspace layout (bf16 elements)
  unsigned short* ws  = (unsigned short*)d_ws;
  unsigned short* xb  = ws;                        // 4096*2048
  unsigned short* wqb = xb + (size_t)8388608;      // 6144*2048
  unsigned short* wob = wqb + (size_t)12582912;    // 2048*2048
  unsigned short* Qb  = wob + (size_t)4194304;     // [32,2048,128]
  unsigned short* Kb  = Qb + (size_t)8388608;      // [32,2048,128]
  unsigned short* Vtb = Kb + (size_t)8388608;      // [32,128,2048] (transposed)
  unsigned short* Yb  = Vtb + (size_t)8388608;     // [4096,2048]

  cvt_bf16<<<1024, 256, 0, stream>>>(x, xb, 8388608 / 8);
  cvt_bf16<<<1024, 256, 0, stream>>>(wqkv, wqb, 12582912 / 8);
  cvt_bf16<<<512, 256, 0, stream>>>(wout, wob, 4194304 / 8);
  gemm_qkv<<<1536, 256, 0, stream>>>(xb, wqb, Qb, Kb, Vtb);
  attn_kernel<<<512, 256, 0, stream>>>(Qb, Kb, Vtb, Yb);
  gemm_out<<<512, 256, 0, stream>>>(Yb, wob, out);
}

// Round 7
// 286.087 us; speedup vs baseline: 1.4013x; 1.4013x over previous
//
#include <hip/hip_runtime.h>
#include <stdint.h>

// SoftmaxAttention: x[2,2048,2048] f32, w_qkv[6144,2048] f32, w_out[2048,2048] f32
// out[2,2048,2048] f32.  All matmul-shaped compute via bf16 MFMA 16x16x32.

typedef __attribute__((ext_vector_type(8))) short bf16x8;
typedef __attribute__((ext_vector_type(8))) unsigned short u16x8;
typedef __attribute__((ext_vector_type(4))) unsigned short u16x4;
typedef __attribute__((ext_vector_type(4))) float f32x4;

#define MFMA16(a, b, c) __builtin_amdgcn_mfma_f32_16x16x32_bf16((a), (b), (c), 0, 0, 0)

__device__ __forceinline__ unsigned short f2bf(float f) {
  union { float f; uint32_t u; } v; v.f = f;
  uint32_t r = v.u + 0x7FFFu + ((v.u >> 16) & 1u);  // RNE
  return (unsigned short)(r >> 16);
}

__device__ __forceinline__ void gld_lds16(const unsigned short* g, unsigned short* lds) {
  __builtin_amdgcn_global_load_lds(
      (const __attribute__((address_space(1))) void*)g,
      (__attribute__((address_space(3))) void*)lds, 16, 0, 0);
}

// ---------------------------------------------------------------- cvt f32->bf16
__global__ __launch_bounds__(256) void cvt_bf16(const float* __restrict__ in,
                                                unsigned short* __restrict__ out, int n8) {
  int stride = gridDim.x * blockDim.x;
  for (int i = blockIdx.x * blockDim.x + threadIdx.x; i < n8; i += stride) {
    float4 a = reinterpret_cast<const float4*>(in)[i * 2];
    float4 b = reinterpret_cast<const float4*>(in)[i * 2 + 1];
    u16x8 o;
    o[0] = f2bf(a.x); o[1] = f2bf(a.y); o[2] = f2bf(a.z); o[3] = f2bf(a.w);
    o[4] = f2bf(b.x); o[5] = f2bf(b.y); o[6] = f2bf(b.z); o[7] = f2bf(b.w);
    reinterpret_cast<u16x8*>(out)[i] = o;
  }
}

// --------------------------------------------------- 128x128 bf16 GEMM core (B^T)
// R1's measured-best core: single-buffered, stage -> sync -> compute -> sync.
// 256 threads, 4 waves (2x2 of 64x64), BK=32.  Granule swizzle both sides
// (rule #21): measured 0 bank conflicts.
__device__ __forceinline__ void gemm128_core(const unsigned short* __restrict__ A,
                                             const unsigned short* __restrict__ Bt,
                                             int K, int brow, int bcol,
                                             unsigned short* lds_a, unsigned short* lds_b,
                                             f32x4 acc[4][4]) {
  const int tid = threadIdx.x;
  const int l   = tid & 63;
  const int w   = tid >> 6;
  const int wr  = (w >> 1) << 6;
  const int wc  = (w & 1) << 6;

  const int srow = tid >> 2;                       // staging row within 64-row chunk
  const int sswz = (tid & 3) ^ ((srow >> 1) & 3);  // swizzled 16B granule
  const unsigned short* gA0 = A  + (size_t)(brow + srow) * K + 8 * sswz;
  const unsigned short* gA1 = gA0 + (size_t)64 * K;
  const unsigned short* gB0 = Bt + (size_t)(bcol + srow) * K + 8 * sswz;
  const unsigned short* gB1 = gB0 + (size_t)64 * K;

  unsigned short* la0 = lds_a + tid * 8;
  unsigned short* la1 = lds_a + (256 + tid) * 8;
  unsigned short* lb0 = lds_b + tid * 8;
  unsigned short* lb1 = lds_b + (256 + tid) * 8;

  const int fm    = l & 15;
  const int fswz8 = 8 * ((l >> 4) ^ ((fm >> 1) & 3));

  for (int k0 = 0; k0 < K; k0 += 32) {
    gld_lds16(gA0, la0);
    gld_lds16(gA1, la1);
    gld_lds16(gB0, lb0);
    gld_lds16(gB1, lb1);
    gA0 += 32; gA1 += 32; gB0 += 32; gB1 += 32;
    __syncthreads();  // drains vmcnt(0): staged data visible
    bf16x8 af[4], bfv[4];
#pragma unroll
    for (int i = 0; i < 4; i++)
      af[i] = *(const bf16x8*)&lds_a[(wr + i * 16 + fm) * 32 + fswz8];
#pragma unroll
    for (int j = 0; j < 4; j++)
      bfv[j] = *(const bf16x8*)&lds_b[(wc + j * 16 + fm) * 32 + fswz8];
#pragma unroll
    for (int i = 0; i < 4; i++)
#pragma unroll
      for (int j = 0; j < 4; j++)
        acc[i][j] = MFMA16(af[i], bfv[j], acc[i][j]);
    __syncthreads();
  }
}

// --------------------------------------------------------------- QKV projection
__global__ __launch_bounds__(256) void gemm_qkv(const unsigned short* __restrict__ xb,
                                                const unsigned short* __restrict__ wqb,
                                                unsigned short* __restrict__ Qb,
                                                unsigned short* __restrict__ Kb,
                                                unsigned short* __restrict__ Vtb) {
  __shared__ alignas(16) unsigned short lds_a[128 * 32];
  __shared__ alignas(16) unsigned short lds_b[128 * 32];
  f32x4 acc[4][4];
#pragma unroll
  for (int i = 0; i < 4; i++)
#pragma unroll
    for (int j = 0; j < 4; j++) acc[i][j] = (f32x4){0.f, 0.f, 0.f, 0.f};

  const int brow = blockIdx.y << 7;
  const int bcol = blockIdx.x << 7;
  gemm128_core(xb, wqb, 2048, brow, bcol, lds_a, lds_b, acc);

  const int l = threadIdx.x & 63;
  const int w = threadIdx.x >> 6;
  const int wr = (w >> 1) << 6, wc = (w & 1) << 6;
  const int which = bcol >> 11;                         // 0=Q 1=K 2=V (block-uniform)
  const int bh = ((brow >> 11) << 4) | ((bcol >> 7) & 15);
  const int tbase = (brow & 2047) + wr + ((l >> 4) << 2);

#pragma unroll
  for (int i = 0; i < 4; i++) {
    const int t0 = tbase + i * 16;
#pragma unroll
    for (int j = 0; j < 4; j++) {
      const int d = wc + j * 16 + (l & 15);
      if (which == 2) {
        u16x4 pk;
#pragma unroll
        for (int r = 0; r < 4; r++) pk[r] = f2bf(acc[i][j][r]);
        *reinterpret_cast<u16x4*>(&Vtb[((size_t)bh * 128 + d) * 2048 + t0]) = pk;
      } else {
        unsigned short* dst = (which == 0 ? Qb : Kb) + ((size_t)bh * 2048 + t0) * 128 + d;
#pragma unroll
        for (int r = 0; r < 4; r++) dst[(size_t)r * 128] = f2bf(acc[i][j][r]);
      }
    }
  }
}

// -------------------------------------------------------------- output projection
__global__ __launch_bounds__(256) void gemm_out(const unsigned short* __restrict__ yb,
                                                const unsigned short* __restrict__ wob,
                                                float* __restrict__ out) {
  __shared__ alignas(16) unsigned short lds_a[128 * 32];
  __shared__ alignas(16) unsigned short lds_b[128 * 32];
  f32x4 acc[4][4];
#pragma unroll
  for (int i = 0; i < 4; i++)
#pragma unroll
    for (int j = 0; j < 4; j++) acc[i][j] = (f32x4){0.f, 0.f, 0.f, 0.f};

  const int brow = blockIdx.y << 7;
  const int bcol = blockIdx.x << 7;
  gemm128_core(yb, wob, 2048, brow, bcol, lds_a, lds_b, acc);

  const int l = threadIdx.x & 63;
  const int w = threadIdx.x >> 6;
  const int wr = (w >> 1) << 6, wc = (w & 1) << 6;
#pragma unroll
  for (int i = 0; i < 4; i++) {
    const int m0 = brow + wr + i * 16 + ((l >> 4) << 2);
#pragma unroll
    for (int j = 0; j < 4; j++) {
      const int n = bcol + wc + j * 16 + (l & 15);
#pragma unroll
      for (int r = 0; r < 4; r++) out[(size_t)(m0 + r) * 2048 + n] = acc[i][j][r];
    }
  }
}

// ------------------------------------------------------------------ flash attn
// PAIRED causal tiles (j, 31-j) => 33 kv-steps/block, perfect balance.
// K AND V double-buffered in LDS: stage(t+1) issued before compute(t),
// ONE vmcnt(0)+barrier per step (was 2).  LDS 72 KiB; grid 512 = 2 blocks/CU
// regardless, so no occupancy cost.  T13 defer-max: skip rescale when all
// row-max growth <= 8 (log2 domain).
__device__ __forceinline__ void stage_kv64(const unsigned short* __restrict__ Kg,
                                           const unsigned short* __restrict__ Vg,
                                           int kv0, unsigned short* dk,
                                           unsigned short* dv, int tid) {
#pragma unroll
  for (int c = 0; c < 4; c++) {
    int s = c * 256 + tid;
    int row = s >> 4, g = s & 15;
    gld_lds16(&Kg[(size_t)(kv0 + row) * 128 + 8 * (g ^ (row & 7))], &dk[s * 8]);
  }
#pragma unroll
  for (int c = 0; c < 4; c++) {
    int s = c * 256 + tid;
    int row = s >> 3, g = s & 7;
    gld_lds16(&Vg[(size_t)row * 2048 + kv0 + 8 * (g ^ (row & 7))], &dv[s * 8]);
  }
}

__global__ __launch_bounds__(256) void attn_kernel(const unsigned short* __restrict__ Qb,
                                                   const unsigned short* __restrict__ Kb,
                                                   const unsigned short* __restrict__ Vtb,
                                                   unsigned short* __restrict__ Yb) {
  __shared__ alignas(16) unsigned short lds_k[2][64 * 128];
  __shared__ alignas(16) unsigned short lds_v[2][128 * 64];
  __shared__ alignas(16) unsigned short p_lds[4][16 * 64];

  const int tid = threadIdx.x;
  const int l = tid & 63;
  const int w = tid >> 6;

  const int bid = blockIdx.x;                // 0..511
  const int xcd = bid & 7;
  const int loc = bid >> 3;                  // 0..63
  const int bh = xcd * 4 + (loc >> 4);       // 0..31
  const int jidx = loc & 15;                 // 0..15

  const int b = bh >> 4, h = bh & 15;
  const float SC = 0.12752585f;  // log2(e)/sqrt(128)

  const unsigned short* Qg = Qb + (size_t)bh * 2048 * 128;
  const unsigned short* Kg = Kb + (size_t)bh * 2048 * 128;
  const unsigned short* Vg = Vtb + (size_t)bh * 128 * 2048;

  for (int ph = 0; ph < 2; ph++) {
    const int h64 = (ph == 0) ? jidx : (31 - jidx);
    const int q0 = h64 << 6;
    const int qw0 = q0 + (w << 4);

    // Q fragments in registers (A-operand: m = l&15, k = ds*32 + 8*(l>>4))
    bf16x8 qf[4];
#pragma unroll
    for (int ds = 0; ds < 4; ds++)
      qf[ds] = *(const bf16x8*)&Qg[(size_t)(qw0 + (l & 15)) * 128 + ds * 32 + 8 * (l >> 4)];

    f32x4 yacc[8];
#pragma unroll
    for (int dt = 0; dt < 8; dt++) yacc[dt] = (f32x4){0.f, 0.f, 0.f, 0.f};
    float mrow[4], lrow[4];
#pragma unroll
    for (int r = 0; r < 4; r++) { mrow[r] = -1e30f; lrow[r] = 0.f; }

    const int nkv = h64 + 1;

    // prologue: stage tile 0
    stage_kv64(Kg, Vg, 0, lds_k[0], lds_v[0], tid);
    asm volatile("s_waitcnt vmcnt(0)" ::: "memory");
    __syncthreads();

    for (int t = 0; t < nkv; t++) {
      const int kv0 = t << 6;
      const int buf = t & 1;
      const unsigned short* kb = lds_k[buf];
      const unsigned short* vb = lds_v[buf];
      if (t + 1 < nkv)
        stage_kv64(Kg, Vg, kv0 + 64, lds_k[buf ^ 1], lds_v[buf ^ 1], tid);

      if (kv0 <= qw0 + 15) {  // wave has at least one unmasked row
        // S = Q K^T : 16 MFMA
        f32x4 sfr[4];
#pragma unroll
        for (int kt = 0; kt < 4; kt++) {
          const int kr = kt * 16 + (l & 15);
          f32x4 s4 = (f32x4){0.f, 0.f, 0.f, 0.f};
#pragma unroll
          for (int ds = 0; ds < 4; ds++) {
            bf16x8 kfr = *(const bf16x8*)&kb[kr * 128 + 8 * (((ds << 2) + (l >> 4)) ^ (kr & 7))];
            s4 = MFMA16(qf[ds], kfr, s4);
          }
          sfr[kt] = s4;
        }
        const bool need_mask = (kv0 + 63 > qw0);
#pragma unroll
        for (int kt = 0; kt < 4; kt++)
#pragma unroll
          for (int r = 0; r < 4; r++) {
            float sv = sfr[kt][r] * SC;
            if (need_mask) {
              int qa = qw0 + ((l >> 4) << 2) + r;
              int ka = kv0 + kt * 16 + (l & 15);
              sv = (ka > qa) ? -1e30f : sv;
            }
            sfr[kt][r] = sv;
          }
        // online softmax (log2 domain); rows at (l>>4)*4 + r, cols on l&15
        float rmax[4];
#pragma unroll
        for (int r = 0; r < 4; r++) {
          float m = fmaxf(fmaxf(sfr[0][r], sfr[1][r]), fmaxf(sfr[2][r], sfr[3][r]));
          m = fmaxf(m, __shfl_xor(m, 1));
          m = fmaxf(m, __shfl_xor(m, 2));
          m = fmaxf(m, __shfl_xor(m, 4));
          m = fmaxf(m, __shfl_xor(m, 8));
          rmax[r] = m;
        }
        // T13 defer-max: wave-uniform skip of rescale when growth <= 8
        bool sm = (rmax[0] <= mrow[0] + 8.f) && (rmax[1] <= mrow[1] + 8.f) &&
                  (rmax[2] <= mrow[2] + 8.f) && (rmax[3] <= mrow[3] + 8.f);
        if (!__all(sm)) {
          float f[4];
#pragma unroll
          for (int r = 0; r < 4; r++) {
            float mn = fmaxf(mrow[r], rmax[r]);
            f[r] = exp2f(mrow[r] - mn);
            mrow[r] = mn;
            lrow[r] *= f[r];
          }
#pragma unroll
          for (int dt = 0; dt < 8; dt++)
#pragma unroll
            for (int r = 0; r < 4; r++) yacc[dt][r] *= f[r];
        }
        // P = exp2(S - m) (bounded by 2^8 when deferred), stash bf16 to LDS
        float rsum[4] = {0.f, 0.f, 0.f, 0.f};
#pragma unroll
        for (int kt = 0; kt < 4; kt++)
#pragma unroll
          for (int r = 0; r < 4; r++) {
            float p = exp2f(sfr[kt][r] - mrow[r]);
            rsum[r] += p;
            int row = ((l >> 4) << 2) + r;
            int k = kt * 16 + (l & 15);
            p_lds[w][row * 64 + (((k >> 3) ^ (row & 7)) << 3) + (k & 7)] = f2bf(p);
          }
#pragma unroll
        for (int r = 0; r < 4; r++) {
          float s = rsum[r];
          s += __shfl_xor(s, 1);
          s += __shfl_xor(s, 2);
          s += __shfl_xor(s, 4);
          s += __shfl_xor(s, 8);
          lrow[r] += s;
        }

        // cross-lane LDS write->read fence (same wave)
        asm volatile("s_waitcnt lgkmcnt(0)" ::: "memory");
        __builtin_amdgcn_sched_barrier(0);

        // PV: 16 MFMA.  A = P (m = l&15, k = ks*32+8*(l>>4)), B = V from V^T LDS
#pragma unroll
        for (int ks = 0; ks < 2; ks++) {
          const int prow = l & 15;
          bf16x8 pa = *(const bf16x8*)&p_lds[w][prow * 64 + ((((ks << 2) + (l >> 4)) ^ (prow & 7)) << 3)];
#pragma unroll
          for (int dt = 0; dt < 8; dt++) {
            const int d = dt * 16 + (l & 15);
            bf16x8 vv = *(const bf16x8*)&vb[d * 64 + ((((ks << 2) + (l >> 4)) ^ (d & 7)) << 3)];
            yacc[dt] = MFMA16(pa, vv, yacc[dt]);
          }
        }
      }
      // one wait+barrier per step: next tile staged, all waves done with buf
      asm volatile("s_waitcnt vmcnt(0)" ::: "memory");
      __syncthreads();
    }
    // epilogue: y = acc / l, bf16 into [B,T,C] (C index = h*128 + d)
#pragma unroll
    for (int dt = 0; dt < 8; dt++)
#pragma unroll
      for (int r = 0; r < 4; r++) {
        int qa = qw0 + ((l >> 4) << 2) + r;
        Yb[((size_t)(b * 2048 + qa)) * 2048 + h * 128 + dt * 16 + (l & 15)] =
            f2bf(yacc[dt][r] / lrow[r]);
      }
  }
}

// ---------------------------------------------------------------------- launch
extern "C" void kernel_launch(void* const* d_in, const int* in_sizes, int n_in,
                              void* d_out, int out_size, void* d_ws, size_t ws_size,
                              hipStream_t stream) {
  const float* x    = (const float*)d_in[0];
  const float* wqkv = (const float*)d_in[1];
  const float* wout = (const float*)d_in[2];
  float* out = (float*)d_out;

  // workspace layout (bf16 elements)
  unsigned short* ws  = (unsigned short*)d_ws;
  unsigned short* xb  = ws;                        // 4096*2048
  unsigned short* wqb = xb + (size_t)8388608;      // 6144*2048
  unsigned short* wob = wqb + (size_t)12582912;    // 2048*2048
  unsigned short* Qb  = wob + (size_t)4194304;     // [32,2048,128]
  unsigned short* Kb  = Qb + (size_t)8388608;      // [32,2048,128]
  unsigned short* Vtb = Kb + (size_t)8388608;      // [32,128,2048] (transposed)
  unsigned short* Yb  = Vtb + (size_t)8388608;     // [4096,2048]

  cvt_bf16<<<1024, 256, 0, stream>>>(x, xb, 8388608 / 8);
  cvt_bf16<<<1024, 256, 0, stream>>>(wqkv, wqb, 12582912 / 8);
  cvt_bf16<<<512, 256, 0, stream>>>(wout, wob, 4194304 / 8);
  gemm_qkv<<<dim3(48, 32), 256, 0, stream>>>(xb, wqb, Qb, Kb, Vtb);
  attn_kernel<<<512, 256, 0, stream>>>(Qb, Kb, Vtb, Yb);
  gemm_out<<<dim3(16, 32), 256, 0, stream>>>(Yb, wob, out);
}

// Round 8
// 284.292 us; speedup vs baseline: 1.4101x; 1.0063x over previous
//
#include <hip/hip_runtime.h>
#include <stdint.h>

// SoftmaxAttention: x[2,2048,2048] f32, w_qkv[6144,2048] f32, w_out[2048,2048] f32
// out[2,2048,2048] f32.  All matmul-shaped compute via bf16 MFMA 16x16x32.

typedef __attribute__((ext_vector_type(8))) short bf16x8;
typedef __attribute__((ext_vector_type(8))) unsigned short u16x8;
typedef __attribute__((ext_vector_type(4))) unsigned short u16x4;
typedef __attribute__((ext_vector_type(4))) float f32x4;

#define MFMA16(a, b, c) __builtin_amdgcn_mfma_f32_16x16x32_bf16((a), (b), (c), 0, 0, 0)

__device__ __forceinline__ unsigned short f2bf(float f) {
  union { float f; uint32_t u; } v; v.f = f;
  uint32_t r = v.u + 0x7FFFu + ((v.u >> 16) & 1u);  // RNE
  return (unsigned short)(r >> 16);
}

__device__ __forceinline__ void gld_lds16(const unsigned short* g, unsigned short* lds) {
  __builtin_amdgcn_global_load_lds(
      (const __attribute__((address_space(1))) void*)g,
      (__attribute__((address_space(3))) void*)lds, 16, 0, 0);
}

// ---------------------------------------------------------------- cvt f32->bf16
__global__ __launch_bounds__(256) void cvt_bf16(const float* __restrict__ in,
                                                unsigned short* __restrict__ out, int n8) {
  int stride = gridDim.x * blockDim.x;
  for (int i = blockIdx.x * blockDim.x + threadIdx.x; i < n8; i += stride) {
    float4 a = reinterpret_cast<const float4*>(in)[i * 2];
    float4 b = reinterpret_cast<const float4*>(in)[i * 2 + 1];
    u16x8 o;
    o[0] = f2bf(a.x); o[1] = f2bf(a.y); o[2] = f2bf(a.z); o[3] = f2bf(a.w);
    o[4] = f2bf(b.x); o[5] = f2bf(b.y); o[6] = f2bf(b.z); o[7] = f2bf(b.w);
    reinterpret_cast<u16x8*>(out)[i] = o;
  }
}

// --------------------------------------------------- 128x128 bf16 GEMM core (B^T)
// R1's measured-best core: single-buffered, stage -> sync -> compute -> sync.
__device__ __forceinline__ void gemm128_core(const unsigned short* __restrict__ A,
                                             const unsigned short* __restrict__ Bt,
                                             int K, int brow, int bcol,
                                             unsigned short* lds_a, unsigned short* lds_b,
                                             f32x4 acc[4][4]) {
  const int tid = threadIdx.x;
  const int l   = tid & 63;
  const int w   = tid >> 6;
  const int wr  = (w >> 1) << 6;
  const int wc  = (w & 1) << 6;

  const int srow = tid >> 2;                       // staging row within 64-row chunk
  const int sswz = (tid & 3) ^ ((srow >> 1) & 3);  // swizzled 16B granule
  const unsigned short* gA0 = A  + (size_t)(brow + srow) * K + 8 * sswz;
  const unsigned short* gA1 = gA0 + (size_t)64 * K;
  const unsigned short* gB0 = Bt + (size_t)(bcol + srow) * K + 8 * sswz;
  const unsigned short* gB1 = gB0 + (size_t)64 * K;

  unsigned short* la0 = lds_a + tid * 8;
  unsigned short* la1 = lds_a + (256 + tid) * 8;
  unsigned short* lb0 = lds_b + tid * 8;
  unsigned short* lb1 = lds_b + (256 + tid) * 8;

  const int fm    = l & 15;
  const int fswz8 = 8 * ((l >> 4) ^ ((fm >> 1) & 3));

  for (int k0 = 0; k0 < K; k0 += 32) {
    gld_lds16(gA0, la0);
    gld_lds16(gA1, la1);
    gld_lds16(gB0, lb0);
    gld_lds16(gB1, lb1);
    gA0 += 32; gA1 += 32; gB0 += 32; gB1 += 32;
    __syncthreads();  // drains vmcnt(0): staged data visible
    bf16x8 af[4], bfv[4];
#pragma unroll
    for (int i = 0; i < 4; i++)
      af[i] = *(const bf16x8*)&lds_a[(wr + i * 16 + fm) * 32 + fswz8];
#pragma unroll
    for (int j = 0; j < 4; j++)
      bfv[j] = *(const bf16x8*)&lds_b[(wc + j * 16 + fm) * 32 + fswz8];
#pragma unroll
    for (int i = 0; i < 4; i++)
#pragma unroll
      for (int j = 0; j < 4; j++)
        acc[i][j] = MFMA16(af[i], bfv[j], acc[i][j]);
    __syncthreads();
  }
}

// --------------------------------------------------------------- QKV projection
__global__ __launch_bounds__(256) void gemm_qkv(const unsigned short* __restrict__ xb,
                                                const unsigned short* __restrict__ wqb,
                                                unsigned short* __restrict__ Qb,
                                                unsigned short* __restrict__ Kb,
                                                unsigned short* __restrict__ Vtb) {
  __shared__ alignas(16) unsigned short lds_a[128 * 32];
  __shared__ alignas(16) unsigned short lds_b[128 * 32];
  f32x4 acc[4][4];
#pragma unroll
  for (int i = 0; i < 4; i++)
#pragma unroll
    for (int j = 0; j < 4; j++) acc[i][j] = (f32x4){0.f, 0.f, 0.f, 0.f};

  const int brow = blockIdx.y << 7;
  const int bcol = blockIdx.x << 7;
  gemm128_core(xb, wqb, 2048, brow, bcol, lds_a, lds_b, acc);

  const int l = threadIdx.x & 63;
  const int w = threadIdx.x >> 6;
  const int wr = (w >> 1) << 6, wc = (w & 1) << 6;
  const int which = bcol >> 11;                         // 0=Q 1=K 2=V (block-uniform)
  const int bh = ((brow >> 11) << 4) | ((bcol >> 7) & 15);
  const int tbase = (brow & 2047) + wr + ((l >> 4) << 2);

#pragma unroll
  for (int i = 0; i < 4; i++) {
    const int t0 = tbase + i * 16;
#pragma unroll
    for (int j = 0; j < 4; j++) {
      const int d = wc + j * 16 + (l & 15);
      if (which == 2) {
        u16x4 pk;
#pragma unroll
        for (int r = 0; r < 4; r++) pk[r] = f2bf(acc[i][j][r]);
        *reinterpret_cast<u16x4*>(&Vtb[((size_t)bh * 128 + d) * 2048 + t0]) = pk;
      } else {
        unsigned short* dst = (which == 0 ? Qb : Kb) + ((size_t)bh * 2048 + t0) * 128 + d;
#pragma unroll
        for (int r = 0; r < 4; r++) dst[(size_t)r * 128] = f2bf(acc[i][j][r]);
      }
    }
  }
}

// -------------------------------------------------------------- output projection
__global__ __launch_bounds__(256) void gemm_out(const unsigned short* __restrict__ yb,
                                                const unsigned short* __restrict__ wob,
                                                float* __restrict__ out) {
  __shared__ alignas(16) unsigned short lds_a[128 * 32];
  __shared__ alignas(16) unsigned short lds_b[128 * 32];
  f32x4 acc[4][4];
#pragma unroll
  for (int i = 0; i < 4; i++)
#pragma unroll
    for (int j = 0; j < 4; j++) acc[i][j] = (f32x4){0.f, 0.f, 0.f, 0.f};

  const int brow = blockIdx.y << 7;
  const int bcol = blockIdx.x << 7;
  gemm128_core(yb, wob, 2048, brow, bcol, lds_a, lds_b, acc);

  const int l = threadIdx.x & 63;
  const int w = threadIdx.x >> 6;
  const int wr = (w >> 1) << 6, wc = (w & 1) << 6;
#pragma unroll
  for (int i = 0; i < 4; i++) {
    const int m0 = brow + wr + i * 16 + ((l >> 4) << 2);
#pragma unroll
    for (int j = 0; j < 4; j++) {
      const int n = bcol + wc + j * 16 + (l & 15);
#pragma unroll
      for (int r = 0; r < 4; r++) out[(size_t)(m0 + r) * 2048 + n] = acc[i][j][r];
    }
  }
}

// ------------------------------------------------------------------ flash attn
// MERGED causal pair: one kv-loop serves tiles j and 31-j (shared kv prefix
// 0..j staged ONCE).  Staged tiles/block: 32-j (mean 24.5 vs 33 = -26%
// staging + barriers); compute work/block constant (33 wave-tile-steps).
// K,V double-buffered; one vmcnt(0)+barrier per step.  T13 defer-max.
// T5 setprio around MFMA.  LDS 72 KiB -> 2 blocks/CU; ~200 VGPR -> 2 w/SIMD.
__device__ __forceinline__ void stage_kv64(const unsigned short* __restrict__ Kg,
                                           const unsigned short* __restrict__ Vg,
                                           int kv0, unsigned short* dk,
                                           unsigned short* dv, int tid) {
#pragma unroll
  for (int c = 0; c < 4; c++) {
    int s = c * 256 + tid;
    int row = s >> 4, g = s & 15;
    gld_lds16(&Kg[(size_t)(kv0 + row) * 128 + 8 * (g ^ (row & 7))], &dk[s * 8]);
  }
#pragma unroll
  for (int c = 0; c < 4; c++) {
    int s = c * 256 + tid;
    int row = s >> 3, g = s & 7;
    gld_lds16(&Vg[(size_t)row * 2048 + kv0 + 8 * (g ^ (row & 7))], &dv[s * 8]);
  }
}

// one q-tile's contribution for one kv-tile (QK^T -> online softmax -> PV)
__device__ __forceinline__ void attn_tile_step(const bf16x8 qf[4], f32x4 yacc[8],
                                               float mrow[4], float lrow[4],
                                               int qw0, int kv0,
                                               const unsigned short* kb,
                                               const unsigned short* vb,
                                               unsigned short* pw, int l) {
  const float SC = 0.12752585f;  // log2(e)/sqrt(128)
  // S = Q K^T : 16 MFMA
  f32x4 sfr[4];
  __builtin_amdgcn_s_setprio(1);
#pragma unroll
  for (int kt = 0; kt < 4; kt++) {
    const int kr = kt * 16 + (l & 15);
    f32x4 s4 = (f32x4){0.f, 0.f, 0.f, 0.f};
#pragma unroll
    for (int ds = 0; ds < 4; ds++) {
      bf16x8 kfr = *(const bf16x8*)&kb[kr * 128 + 8 * (((ds << 2) + (l >> 4)) ^ (kr & 7))];
      s4 = MFMA16(qf[ds], kfr, s4);
    }
    sfr[kt] = s4;
  }
  __builtin_amdgcn_s_setprio(0);
  const bool need_mask = (kv0 + 63 > qw0);
#pragma unroll
  for (int kt = 0; kt < 4; kt++)
#pragma unroll
    for (int r = 0; r < 4; r++) {
      float sv = sfr[kt][r] * SC;
      if (need_mask) {
        int qa = qw0 + ((l >> 4) << 2) + r;
        int ka = kv0 + kt * 16 + (l & 15);
        sv = (ka > qa) ? -1e30f : sv;
      }
      sfr[kt][r] = sv;
    }
  // row max (rows at (l>>4)*4 + r, cols on l&15)
  float rmax[4];
#pragma unroll
  for (int r = 0; r < 4; r++) {
    float m = fmaxf(fmaxf(sfr[0][r], sfr[1][r]), fmaxf(sfr[2][r], sfr[3][r]));
    m = fmaxf(m, __shfl_xor(m, 1));
    m = fmaxf(m, __shfl_xor(m, 2));
    m = fmaxf(m, __shfl_xor(m, 4));
    m = fmaxf(m, __shfl_xor(m, 8));
    rmax[r] = m;
  }
  // T13 defer-max: wave-uniform skip of rescale when growth <= 8
  bool sm = (rmax[0] <= mrow[0] + 8.f) && (rmax[1] <= mrow[1] + 8.f) &&
            (rmax[2] <= mrow[2] + 8.f) && (rmax[3] <= mrow[3] + 8.f);
  if (!__all(sm)) {
    float f[4];
#pragma unroll
    for (int r = 0; r < 4; r++) {
      float mn = fmaxf(mrow[r], rmax[r]);
      f[r] = exp2f(mrow[r] - mn);
      mrow[r] = mn;
      lrow[r] *= f[r];
    }
#pragma unroll
    for (int dt = 0; dt < 8; dt++)
#pragma unroll
      for (int r = 0; r < 4; r++) yacc[dt][r] *= f[r];
  }
  // P = exp2(S - m) (bounded by 2^8 when deferred), stash bf16 to LDS
  float rsum[4] = {0.f, 0.f, 0.f, 0.f};
#pragma unroll
  for (int kt = 0; kt < 4; kt++)
#pragma unroll
    for (int r = 0; r < 4; r++) {
      float p = exp2f(sfr[kt][r] - mrow[r]);
      rsum[r] += p;
      int row = ((l >> 4) << 2) + r;
      int k = kt * 16 + (l & 15);
      pw[row * 64 + (((k >> 3) ^ (row & 7)) << 3) + (k & 7)] = f2bf(p);
    }
#pragma unroll
  for (int r = 0; r < 4; r++) {
    float s = rsum[r];
    s += __shfl_xor(s, 1);
    s += __shfl_xor(s, 2);
    s += __shfl_xor(s, 4);
    s += __shfl_xor(s, 8);
    lrow[r] += s;
  }
  // cross-lane LDS write->read fence (same wave)
  asm volatile("s_waitcnt lgkmcnt(0)" ::: "memory");
  __builtin_amdgcn_sched_barrier(0);
  // PV: 16 MFMA.  A = P, B = V from V^T LDS
  __builtin_amdgcn_s_setprio(1);
#pragma unroll
  for (int ks = 0; ks < 2; ks++) {
    const int prow = l & 15;
    bf16x8 pa = *(const bf16x8*)&pw[prow * 64 + ((((ks << 2) + (l >> 4)) ^ (prow & 7)) << 3)];
#pragma unroll
    for (int dt = 0; dt < 8; dt++) {
      const int d = dt * 16 + (l & 15);
      bf16x8 vv = *(const bf16x8*)&vb[d * 64 + ((((ks << 2) + (l >> 4)) ^ (d & 7)) << 3)];
      yacc[dt] = MFMA16(pa, vv, yacc[dt]);
    }
  }
  __builtin_amdgcn_s_setprio(0);
  // ensure PV's pa read retired before caller's next pw overwrite (in-order DS
  // pipe per wave makes this a no-op in practice; fence is free vs correctness)
  asm volatile("s_waitcnt lgkmcnt(0)" ::: "memory");
}

__global__ __launch_bounds__(256, 2) void attn_kernel(const unsigned short* __restrict__ Qb,
                                                      const unsigned short* __restrict__ Kb,
                                                      const unsigned short* __restrict__ Vtb,
                                                      unsigned short* __restrict__ Yb) {
  __shared__ alignas(16) unsigned short lds_k[2][64 * 128];
  __shared__ alignas(16) unsigned short lds_v[2][128 * 64];
  __shared__ alignas(16) unsigned short p_lds[4][16 * 64];

  const int tid = threadIdx.x;
  const int l = tid & 63;
  const int w = tid >> 6;

  const int bid = blockIdx.x;                // 0..511
  const int xcd = bid & 7;
  const int loc = bid >> 3;                  // 0..63
  const int bh = xcd * 4 + (loc >> 4);       // 0..31
  const int jidx = loc & 15;                 // 0..15

  const int b = bh >> 4, h = bh & 15;

  const unsigned short* Qg = Qb + (size_t)bh * 2048 * 128;
  const unsigned short* Kg = Kb + (size_t)bh * 2048 * 128;
  const unsigned short* Vg = Vtb + (size_t)bh * 128 * 2048;

  const int j_lo = jidx, j_hi = 31 - jidx;
  const int qw0_lo = (j_lo << 6) + (w << 4);
  const int qw0_hi = (j_hi << 6) + (w << 4);

  // Q fragments for both tiles (A-operand: m = l&15, k = ds*32 + 8*(l>>4))
  bf16x8 qf_lo[4], qf_hi[4];
#pragma unroll
  for (int ds = 0; ds < 4; ds++) {
    qf_lo[ds] = *(const bf16x8*)&Qg[(size_t)(qw0_lo + (l & 15)) * 128 + ds * 32 + 8 * (l >> 4)];
    qf_hi[ds] = *(const bf16x8*)&Qg[(size_t)(qw0_hi + (l & 15)) * 128 + ds * 32 + 8 * (l >> 4)];
  }

  f32x4 yacc_lo[8], yacc_hi[8];
#pragma unroll
  for (int dt = 0; dt < 8; dt++) {
    yacc_lo[dt] = (f32x4){0.f, 0.f, 0.f, 0.f};
    yacc_hi[dt] = (f32x4){0.f, 0.f, 0.f, 0.f};
  }
  float mrow_lo[4], lrow_lo[4], mrow_hi[4], lrow_hi[4];
#pragma unroll
  for (int r = 0; r < 4; r++) {
    mrow_lo[r] = -1e30f; lrow_lo[r] = 0.f;
    mrow_hi[r] = -1e30f; lrow_hi[r] = 0.f;
  }

  const int nkv = j_hi + 1;  // 17..32

  // prologue: stage tile 0
  stage_kv64(Kg, Vg, 0, lds_k[0], lds_v[0], tid);
  asm volatile("s_waitcnt vmcnt(0)" ::: "memory");
  __syncthreads();

  for (int t = 0; t < nkv; t++) {
    const int kv0 = t << 6;
    const int buf = t & 1;
    const unsigned short* kb = lds_k[buf];
    const unsigned short* vb = lds_v[buf];
    if (t + 1 < nkv)
      stage_kv64(Kg, Vg, kv0 + 64, lds_k[buf ^ 1], lds_v[buf ^ 1], tid);

    if (kv0 <= qw0_lo + 15)
      attn_tile_step(qf_lo, yacc_lo, mrow_lo, lrow_lo, qw0_lo, kv0, kb, vb, p_lds[w], l);
    attn_tile_step(qf_hi, yacc_hi, mrow_hi, lrow_hi, qw0_hi, kv0, kb, vb, p_lds[w], l);

    // one wait+barrier per step: next tile staged, all waves done with buf
    asm volatile("s_waitcnt vmcnt(0)" ::: "memory");
    __syncthreads();
  }

  // epilogue: y = acc / l, bf16 into [B,T,C] (C index = h*128 + d)
#pragma unroll
  for (int dt = 0; dt < 8; dt++)
#pragma unroll
    for (int r = 0; r < 4; r++) {
      int qa_lo = qw0_lo + ((l >> 4) << 2) + r;
      int qa_hi = qw0_hi + ((l >> 4) << 2) + r;
      Yb[((size_t)(b * 2048 + qa_lo)) * 2048 + h * 128 + dt * 16 + (l & 15)] =
          f2bf(yacc_lo[dt][r] / lrow_lo[r]);
      Yb[((size_t)(b * 2048 + qa_hi)) * 2048 + h * 128 + dt * 16 + (l & 15)] =
          f2bf(yacc_hi[dt][r] / lrow_hi[r]);
    }
}

// ---------------------------------------------------------------------- launch
extern "C" void kernel_launch(void* const* d_in, const int* in_sizes, int n_in,
                              void* d_out, int out_size, void* d_ws, size_t ws_size,
                              hipStream_t stream) {
  const float* x    = (const float*)d_in[0];
  const float* wqkv = (const float*)d_in[1];
  const float* wout = (const float*)d_in[2];
  float* out = (float*)d_out;

  // workspace layout (bf16 elements)
  unsigned short* ws  = (unsigned short*)d_ws;
  unsigned short* xb  = ws;                        // 4096*2048
  unsigned short* wqb = xb + (size_t)8388608;      // 6144*2048
  unsigned short* wob = wqb + (size_t)12582912;    // 2048*2048
  unsigned short* Qb  = wob + (size_t)4194304;     // [32,2048,128]
  unsigned short* Kb  = Qb + (size_t)8388608;      // [32,2048,128]
  unsigned short* Vtb = Kb + (size_t)8388608;      // [32,128,2048] (transposed)
  unsigned short* Yb  = Vtb + (size_t)8388608;     // [4096,2048]

  cvt_bf16<<<1024, 256, 0, stream>>>(x, xb, 8388608 / 8);
  cvt_bf16<<<1024, 256, 0, stream>>>(wqkv, wqb, 12582912 / 8);
  cvt_bf16<<<512, 256, 0, stream>>>(wout, wob, 4194304 / 8);
  gemm_qkv<<<dim3(48, 32), 256, 0, stream>>>(xb, wqb, Qb, Kb, Vtb);
  attn_kernel<<<512, 256, 0, stream>>>(Qb, Kb, Vtb, Yb);
  gemm_out<<<dim3(16, 32), 256, 0, stream>>>(Yb, wob, out);
}

// Round 9
// 263.920 us; speedup vs baseline: 1.5190x; 1.0772x over previous
//
#include <hip/hip_runtime.h>
#include <stdint.h>

// SoftmaxAttention: x[2,2048,2048] f32, w_qkv[6144,2048] f32, w_out[2048,2048] f32
// out[2,2048,2048] f32.  All matmul-shaped compute via bf16 MFMA 16x16x32.

typedef __attribute__((ext_vector_type(8))) short bf16x8;
typedef __attribute__((ext_vector_type(8))) unsigned short u16x8;
typedef __attribute__((ext_vector_type(4))) unsigned short u16x4;
typedef __attribute__((ext_vector_type(4))) float f32x4;

#define MFMA16(a, b, c) __builtin_amdgcn_mfma_f32_16x16x32_bf16((a), (b), (c), 0, 0, 0)

__device__ __forceinline__ unsigned short f2bf(float f) {
  union { float f; uint32_t u; } v; v.f = f;
  uint32_t r = v.u + 0x7FFFu + ((v.u >> 16) & 1u);  // RNE
  return (unsigned short)(r >> 16);
}

__device__ __forceinline__ void gld_lds16(const unsigned short* g, unsigned short* lds) {
  __builtin_amdgcn_global_load_lds(
      (const __attribute__((address_space(1))) void*)g,
      (__attribute__((address_space(3))) void*)lds, 16, 0, 0);
}

// ---------------------------------------------------------------- cvt f32->bf16
__device__ __forceinline__ void cvt8(const float* __restrict__ in,
                                     unsigned short* __restrict__ out, int i) {
  float4 a = reinterpret_cast<const float4*>(in)[i * 2];
  float4 b = reinterpret_cast<const float4*>(in)[i * 2 + 1];
  u16x8 o;
  o[0] = f2bf(a.x); o[1] = f2bf(a.y); o[2] = f2bf(a.z); o[3] = f2bf(a.w);
  o[4] = f2bf(b.x); o[5] = f2bf(b.y); o[6] = f2bf(b.z); o[7] = f2bf(b.w);
  reinterpret_cast<u16x8*>(out)[i] = o;
}

__global__ __launch_bounds__(256) void cvt_all(const float* __restrict__ x,
                                               const float* __restrict__ wq,
                                               const float* __restrict__ wo,
                                               unsigned short* __restrict__ xb,
                                               unsigned short* __restrict__ wqb,
                                               unsigned short* __restrict__ wob) {
  const int stride = gridDim.x * blockDim.x;
  const int t0 = blockIdx.x * blockDim.x + threadIdx.x;
  for (int i = t0; i < 1048576; i += stride) cvt8(x, xb, i);
  for (int i = t0; i < 1572864; i += stride) cvt8(wq, wqb, i);
  for (int i = t0; i < 524288; i += stride) cvt8(wo, wob, i);
}

// --------------------------------------------------- 128x128 bf16 GEMM core (B^T)
// R1's measured-best core: single-buffered, stage -> sync -> compute -> sync.
__device__ __forceinline__ void gemm128_core(const unsigned short* __restrict__ A,
                                             const unsigned short* __restrict__ Bt,
                                             int K, int brow, int bcol,
                                             unsigned short* lds_a, unsigned short* lds_b,
                                             f32x4 acc[4][4]) {
  const int tid = threadIdx.x;
  const int l   = tid & 63;
  const int w   = tid >> 6;
  const int wr  = (w >> 1) << 6;
  const int wc  = (w & 1) << 6;

  const int srow = tid >> 2;                       // staging row within 64-row chunk
  const int sswz = (tid & 3) ^ ((srow >> 1) & 3);  // swizzled 16B granule
  const unsigned short* gA0 = A  + (size_t)(brow + srow) * K + 8 * sswz;
  const unsigned short* gA1 = gA0 + (size_t)64 * K;
  const unsigned short* gB0 = Bt + (size_t)(bcol + srow) * K + 8 * sswz;
  const unsigned short* gB1 = gB0 + (size_t)64 * K;

  unsigned short* la0 = lds_a + tid * 8;
  unsigned short* la1 = lds_a + (256 + tid) * 8;
  unsigned short* lb0 = lds_b + tid * 8;
  unsigned short* lb1 = lds_b + (256 + tid) * 8;

  const int fm    = l & 15;
  const int fswz8 = 8 * ((l >> 4) ^ ((fm >> 1) & 3));

  for (int k0 = 0; k0 < K; k0 += 32) {
    gld_lds16(gA0, la0);
    gld_lds16(gA1, la1);
    gld_lds16(gB0, lb0);
    gld_lds16(gB1, lb1);
    gA0 += 32; gA1 += 32; gB0 += 32; gB1 += 32;
    __syncthreads();  // drains vmcnt(0): staged data visible
    bf16x8 af[4], bfv[4];
#pragma unroll
    for (int i = 0; i < 4; i++)
      af[i] = *(const bf16x8*)&lds_a[(wr + i * 16 + fm) * 32 + fswz8];
#pragma unroll
    for (int j = 0; j < 4; j++)
      bfv[j] = *(const bf16x8*)&lds_b[(wc + j * 16 + fm) * 32 + fswz8];
#pragma unroll
    for (int i = 0; i < 4; i++)
#pragma unroll
      for (int j = 0; j < 4; j++)
        acc[i][j] = MFMA16(af[i], bfv[j], acc[i][j]);
    __syncthreads();
  }
}

// --------------------------------------------------------------- QKV projection
__global__ __launch_bounds__(256) void gemm_qkv(const unsigned short* __restrict__ xb,
                                                const unsigned short* __restrict__ wqb,
                                                unsigned short* __restrict__ Qb,
                                                unsigned short* __restrict__ Kb,
                                                unsigned short* __restrict__ Vtb) {
  __shared__ alignas(16) unsigned short lds_a[128 * 32];
  __shared__ alignas(16) unsigned short lds_b[128 * 32];
  f32x4 acc[4][4];
#pragma unroll
  for (int i = 0; i < 4; i++)
#pragma unroll
    for (int j = 0; j < 4; j++) acc[i][j] = (f32x4){0.f, 0.f, 0.f, 0.f};

  const int brow = blockIdx.y << 7;
  const int bcol = blockIdx.x << 7;
  gemm128_core(xb, wqb, 2048, brow, bcol, lds_a, lds_b, acc);

  const int l = threadIdx.x & 63;
  const int w = threadIdx.x >> 6;
  const int wr = (w >> 1) << 6, wc = (w & 1) << 6;
  const int which = bcol >> 11;                         // 0=Q 1=K 2=V (block-uniform)
  const int bh = ((brow >> 11) << 4) | ((bcol >> 7) & 15);
  const int tbase = (brow & 2047) + wr + ((l >> 4) << 2);

#pragma unroll
  for (int i = 0; i < 4; i++) {
    const int t0 = tbase + i * 16;
#pragma unroll
    for (int j = 0; j < 4; j++) {
      const int d = wc + j * 16 + (l & 15);
      if (which == 2) {
        u16x4 pk;
#pragma unroll
        for (int r = 0; r < 4; r++) pk[r] = f2bf(acc[i][j][r]);
        *reinterpret_cast<u16x4*>(&Vtb[((size_t)bh * 128 + d) * 2048 + t0]) = pk;
      } else {
        unsigned short* dst = (which == 0 ? Qb : Kb) + ((size_t)bh * 2048 + t0) * 128 + d;
#pragma unroll
        for (int r = 0; r < 4; r++) dst[(size_t)r * 128] = f2bf(acc[i][j][r]);
      }
    }
  }
}

// -------------------------------------------------------------- output projection
__global__ __launch_bounds__(256) void gemm_out(const unsigned short* __restrict__ yb,
                                                const unsigned short* __restrict__ wob,
                                                float* __restrict__ out) {
  __shared__ alignas(16) unsigned short lds_a[128 * 32];
  __shared__ alignas(16) unsigned short lds_b[128 * 32];
  f32x4 acc[4][4];
#pragma unroll
  for (int i = 0; i < 4; i++)
#pragma unroll
    for (int j = 0; j < 4; j++) acc[i][j] = (f32x4){0.f, 0.f, 0.f, 0.f};

  const int brow = blockIdx.y << 7;
  const int bcol = blockIdx.x << 7;
  gemm128_core(yb, wob, 2048, brow, bcol, lds_a, lds_b, acc);

  const int l = threadIdx.x & 63;
  const int w = threadIdx.x >> 6;
  const int wr = (w >> 1) << 6, wc = (w & 1) << 6;
#pragma unroll
  for (int i = 0; i < 4; i++) {
    const int m0 = brow + wr + i * 16 + ((l >> 4) << 2);
#pragma unroll
    for (int j = 0; j < 4; j++) {
      const int n = bcol + wc + j * 16 + (l & 15);
#pragma unroll
      for (int r = 0; r < 4; r++) out[(size_t)(m0 + r) * 2048 + n] = acc[i][j][r];
    }
  }
}

// ------------------------------------------------------------------ flash attn
// MERGED causal pair (tiles j, 31-j share kv prefix).  K,V double-buffered,
// one vmcnt(0)+barrier per kv-step.  NEW: (1) defer-max with per-lane cheap
// check -- the 16-shfl max reduce runs ONLY on rescale steps; (2) per-lane
// deferred sum (lsum) reduced once in epilogue, not per step; (3) split P
// buffers for lo/hi so the two chains have no LDS ordering dependency.
// LDS 80 KiB -> 2 blocks/CU.
__device__ __forceinline__ void stage_kv64(const unsigned short* __restrict__ Kg,
                                           const unsigned short* __restrict__ Vg,
                                           int kv0, unsigned short* dk,
                                           unsigned short* dv, int tid) {
#pragma unroll
  for (int c = 0; c < 4; c++) {
    int s = c * 256 + tid;
    int row = s >> 4, g = s & 15;
    gld_lds16(&Kg[(size_t)(kv0 + row) * 128 + 8 * (g ^ (row & 7))], &dk[s * 8]);
  }
#pragma unroll
  for (int c = 0; c < 4; c++) {
    int s = c * 256 + tid;
    int row = s >> 3, g = s & 7;
    gld_lds16(&Vg[(size_t)row * 2048 + kv0 + 8 * (g ^ (row & 7))], &dv[s * 8]);
  }
}

// one q-tile's contribution for one kv-tile (QK^T -> online softmax -> PV)
__device__ __forceinline__ void attn_tile_step(const bf16x8 qf[4], f32x4 yacc[8],
                                               float mrow[4], float lsum[4],
                                               int qw0, int kv0,
                                               const unsigned short* kb,
                                               const unsigned short* vb,
                                               unsigned short* pw, int l) {
  const float SC = 0.12752585f;  // log2(e)/sqrt(128)
  // S = Q K^T : 16 MFMA
  f32x4 sfr[4];
  __builtin_amdgcn_s_setprio(1);
#pragma unroll
  for (int kt = 0; kt < 4; kt++) {
    const int kr = kt * 16 + (l & 15);
    f32x4 s4 = (f32x4){0.f, 0.f, 0.f, 0.f};
#pragma unroll
    for (int ds = 0; ds < 4; ds++) {
      bf16x8 kfr = *(const bf16x8*)&kb[kr * 128 + 8 * (((ds << 2) + (l >> 4)) ^ (kr & 7))];
      s4 = MFMA16(qf[ds], kfr, s4);
    }
    sfr[kt] = s4;
  }
  __builtin_amdgcn_s_setprio(0);
  const bool need_mask = (kv0 + 63 > qw0);
#pragma unroll
  for (int kt = 0; kt < 4; kt++)
#pragma unroll
    for (int r = 0; r < 4; r++) {
      float sv = sfr[kt][r] * SC;
      if (need_mask) {
        int qa = qw0 + ((l >> 4) << 2) + r;
        int ka = kv0 + kt * 16 + (l & 15);
        sv = (ka > qa) ? -1e30f : sv;
      }
      sfr[kt][r] = sv;
    }
  // per-lane partial row max (rows at (l>>4)*4 + r, cols on l&15)
  float prmax[4];
#pragma unroll
  for (int r = 0; r < 4; r++)
    prmax[r] = fmaxf(fmaxf(sfr[0][r], sfr[1][r]), fmaxf(sfr[2][r], sfr[3][r]));
  // T13 defer-max, cheap per-lane check: if every lane's partial max is within
  // mrow+8, the true row max is too -> skip the shfl reduce AND the rescale.
  bool sm = (prmax[0] <= mrow[0] + 8.f) && (prmax[1] <= mrow[1] + 8.f) &&
            (prmax[2] <= mrow[2] + 8.f) && (prmax[3] <= mrow[3] + 8.f);
  if (!__all(sm)) {
    float f[4];
#pragma unroll
    for (int r = 0; r < 4; r++) {
      float m = prmax[r];
      m = fmaxf(m, __shfl_xor(m, 1));
      m = fmaxf(m, __shfl_xor(m, 2));
      m = fmaxf(m, __shfl_xor(m, 4));
      m = fmaxf(m, __shfl_xor(m, 8));
      float mn = fmaxf(mrow[r], m);
      f[r] = exp2f(mrow[r] - mn);   // row-uniform: mrow & m uniform across row
      mrow[r] = mn;
      lsum[r] *= f[r];
    }
#pragma unroll
    for (int dt = 0; dt < 8; dt++)
#pragma unroll
      for (int r = 0; r < 4; r++) yacc[dt][r] *= f[r];
  }
  // P = exp2(S - m) (bounded by 2^8 when deferred); per-lane sum accumulation
#pragma unroll
  for (int kt = 0; kt < 4; kt++)
#pragma unroll
    for (int r = 0; r < 4; r++) {
      float p = exp2f(sfr[kt][r] - mrow[r]);
      lsum[r] += p;
      int row = ((l >> 4) << 2) + r;
      int k = kt * 16 + (l & 15);
      pw[row * 64 + (((k >> 3) ^ (row & 7)) << 3) + (k & 7)] = f2bf(p);
    }
  // cross-lane LDS write->read fence (same wave); rule #18 sched_barrier
  asm volatile("s_waitcnt lgkmcnt(0)" ::: "memory");
  __builtin_amdgcn_sched_barrier(0);
  // PV: 16 MFMA.  A = P, B = V from V^T LDS
  __builtin_amdgcn_s_setprio(1);
#pragma unroll
  for (int ks = 0; ks < 2; ks++) {
    const int prow = l & 15;
    bf16x8 pa = *(const bf16x8*)&pw[prow * 64 + ((((ks << 2) + (l >> 4)) ^ (prow & 7)) << 3)];
#pragma unroll
    for (int dt = 0; dt < 8; dt++) {
      const int d = dt * 16 + (l & 15);
      bf16x8 vv = *(const bf16x8*)&vb[d * 64 + ((((ks << 2) + (l >> 4)) ^ (d & 7)) << 3)];
      yacc[dt] = MFMA16(pa, vv, yacc[dt]);
    }
  }
  __builtin_amdgcn_s_setprio(0);
  // no trailing fence: pw is not reused until after the kv-step __syncthreads
}

__global__ __launch_bounds__(256, 2) void attn_kernel(const unsigned short* __restrict__ Qb,
                                                      const unsigned short* __restrict__ Kb,
                                                      const unsigned short* __restrict__ Vtb,
                                                      unsigned short* __restrict__ Yb) {
  __shared__ alignas(16) unsigned short lds_k[2][64 * 128];
  __shared__ alignas(16) unsigned short lds_v[2][128 * 64];
  __shared__ alignas(16) unsigned short p_lds[8][16 * 64];  // [tile(2)][wave(4)]

  const int tid = threadIdx.x;
  const int l = tid & 63;
  const int w = tid >> 6;

  const int bid = blockIdx.x;                // 0..511
  const int xcd = bid & 7;
  const int loc = bid >> 3;                  // 0..63
  const int bh = xcd * 4 + (loc >> 4);       // 0..31
  const int jidx = loc & 15;                 // 0..15

  const int b = bh >> 4, h = bh & 15;

  const unsigned short* Qg = Qb + (size_t)bh * 2048 * 128;
  const unsigned short* Kg = Kb + (size_t)bh * 2048 * 128;
  const unsigned short* Vg = Vtb + (size_t)bh * 128 * 2048;

  const int j_lo = jidx, j_hi = 31 - jidx;
  const int qw0_lo = (j_lo << 6) + (w << 4);
  const int qw0_hi = (j_hi << 6) + (w << 4);

  // Q fragments for both tiles (A-operand: m = l&15, k = ds*32 + 8*(l>>4))
  bf16x8 qf_lo[4], qf_hi[4];
#pragma unroll
  for (int ds = 0; ds < 4; ds++) {
    qf_lo[ds] = *(const bf16x8*)&Qg[(size_t)(qw0_lo + (l & 15)) * 128 + ds * 32 + 8 * (l >> 4)];
    qf_hi[ds] = *(const bf16x8*)&Qg[(size_t)(qw0_hi + (l & 15)) * 128 + ds * 32 + 8 * (l >> 4)];
  }

  f32x4 yacc_lo[8], yacc_hi[8];
#pragma unroll
  for (int dt = 0; dt < 8; dt++) {
    yacc_lo[dt] = (f32x4){0.f, 0.f, 0.f, 0.f};
    yacc_hi[dt] = (f32x4){0.f, 0.f, 0.f, 0.f};
  }
  float mrow_lo[4], lsum_lo[4], mrow_hi[4], lsum_hi[4];
#pragma unroll
  for (int r = 0; r < 4; r++) {
    mrow_lo[r] = -1e30f; lsum_lo[r] = 0.f;
    mrow_hi[r] = -1e30f; lsum_hi[r] = 0.f;
  }

  const int nkv = j_hi + 1;  // 17..32

  // prologue: stage tile 0
  stage_kv64(Kg, Vg, 0, lds_k[0], lds_v[0], tid);
  asm volatile("s_waitcnt vmcnt(0)" ::: "memory");
  __syncthreads();

  for (int t = 0; t < nkv; t++) {
    const int kv0 = t << 6;
    const int buf = t & 1;
    const unsigned short* kb = lds_k[buf];
    const unsigned short* vb = lds_v[buf];
    if (t + 1 < nkv)
      stage_kv64(Kg, Vg, kv0 + 64, lds_k[buf ^ 1], lds_v[buf ^ 1], tid);

    if (kv0 <= qw0_lo + 15)
      attn_tile_step(qf_lo, yacc_lo, mrow_lo, lsum_lo, qw0_lo, kv0, kb, vb, p_lds[w], l);
    attn_tile_step(qf_hi, yacc_hi, mrow_hi, lsum_hi, qw0_hi, kv0, kb, vb, p_lds[4 + w], l);

    // one wait+barrier per step: next tile staged, all waves done with buf
    asm volatile("s_waitcnt vmcnt(0)" ::: "memory");
    __syncthreads();
  }

  // epilogue: reduce deferred sums once, then y = acc / l into [B,T,C]
  float lrow_lo[4], lrow_hi[4];
#pragma unroll
  for (int r = 0; r < 4; r++) {
    float s = lsum_lo[r];
    s += __shfl_xor(s, 1); s += __shfl_xor(s, 2);
    s += __shfl_xor(s, 4); s += __shfl_xor(s, 8);
    lrow_lo[r] = s;
    float u = lsum_hi[r];
    u += __shfl_xor(u, 1); u += __shfl_xor(u, 2);
    u += __shfl_xor(u, 4); u += __shfl_xor(u, 8);
    lrow_hi[r] = u;
  }
#pragma unroll
  for (int dt = 0; dt < 8; dt++)
#pragma unroll
    for (int r = 0; r < 4; r++) {
      int qa_lo = qw0_lo + ((l >> 4) << 2) + r;
      int qa_hi = qw0_hi + ((l >> 4) << 2) + r;
      Yb[((size_t)(b * 2048 + qa_lo)) * 2048 + h * 128 + dt * 16 + (l & 15)] =
          f2bf(yacc_lo[dt][r] / lrow_lo[r]);
      Yb[((size_t)(b * 2048 + qa_hi)) * 2048 + h * 128 + dt * 16 + (l & 15)] =
          f2bf(yacc_hi[dt][r] / lrow_hi[r]);
    }
}

// ---------------------------------------------------------------------- launch
extern "C" void kernel_launch(void* const* d_in, const int* in_sizes, int n_in,
                              void* d_out, int out_size, void* d_ws, size_t ws_size,
                              hipStream_t stream) {
  const float* x    = (const float*)d_in[0];
  const float* wqkv = (const float*)d_in[1];
  const float* wout = (const float*)d_in[2];
  float* out = (float*)d_out;

  // workspace layout (bf16 elements)
  unsigned short* ws  = (unsigned short*)d_ws;
  unsigned short* xb  = ws;                        // 4096*2048
  unsigned short* wqb = xb + (size_t)8388608;      // 6144*2048
  unsigned short* wob = wqb + (size_t)12582912;    // 2048*2048
  unsigned short* Qb  = wob + (size_t)4194304;     // [32,2048,128]
  unsigned short* Kb  = Qb + (size_t)8388608;      // [32,2048,128]
  unsigned short* Vtb = Kb + (size_t)8388608;      // [32,128,2048] (transposed)
  unsigned short* Yb  = Vtb + (size_t)8388608;     // [4096,2048]

  cvt_all<<<2048, 256, 0, stream>>>(x, wqkv, wout, xb, wqb, wob);
  gemm_qkv<<<dim3(48, 32), 256, 0, stream>>>(xb, wqb, Qb, Kb, Vtb);
  attn_kernel<<<512, 256, 0, stream>>>(Qb, Kb, Vtb, Yb);
  gemm_out<<<dim3(16, 32), 256, 0, stream>>>(Yb, wob, out);
}

// Round 10
// 262.336 us; speedup vs baseline: 1.5281x; 1.0060x over previous
//
#include <hip/hip_runtime.h>
#include <stdint.h>

// SoftmaxAttention: x[2,2048,2048] f32, w_qkv[6144,2048] f32, w_out[2048,2048] f32
// out[2,2048,2048] f32.  All matmul-shaped compute via bf16 MFMA 16x16x32.

typedef __attribute__((ext_vector_type(8))) short bf16x8;
typedef __attribute__((ext_vector_type(8))) unsigned short u16x8;
typedef __attribute__((ext_vector_type(4))) unsigned short u16x4;
typedef __attribute__((ext_vector_type(4))) float f32x4;

#define MFMA16(a, b, c) __builtin_amdgcn_mfma_f32_16x16x32_bf16((a), (b), (c), 0, 0, 0)

__device__ __forceinline__ unsigned short f2bf(float f) {
  union { float f; uint32_t u; } v; v.f = f;
  uint32_t r = v.u + 0x7FFFu + ((v.u >> 16) & 1u);  // RNE
  return (unsigned short)(r >> 16);
}

__device__ __forceinline__ void gld_lds16(const unsigned short* g, unsigned short* lds) {
  __builtin_amdgcn_global_load_lds(
      (const __attribute__((address_space(1))) void*)g,
      (__attribute__((address_space(3))) void*)lds, 16, 0, 0);
}

// ---------------------------------------------------------------- cvt f32->bf16
__device__ __forceinline__ void cvt8(const float* __restrict__ in,
                                     unsigned short* __restrict__ out, int i) {
  float4 a = reinterpret_cast<const float4*>(in)[i * 2];
  float4 b = reinterpret_cast<const float4*>(in)[i * 2 + 1];
  u16x8 o;
  o[0] = f2bf(a.x); o[1] = f2bf(a.y); o[2] = f2bf(a.z); o[3] = f2bf(a.w);
  o[4] = f2bf(b.x); o[5] = f2bf(b.y); o[6] = f2bf(b.z); o[7] = f2bf(b.w);
  reinterpret_cast<u16x8*>(out)[i] = o;
}

__global__ __launch_bounds__(256) void cvt_all(const float* __restrict__ x,
                                               const float* __restrict__ wq,
                                               const float* __restrict__ wo,
                                               unsigned short* __restrict__ xb,
                                               unsigned short* __restrict__ wqb,
                                               unsigned short* __restrict__ wob) {
  const int stride = gridDim.x * blockDim.x;
  const int t0 = blockIdx.x * blockDim.x + threadIdx.x;
  for (int i = t0; i < 1048576; i += stride) cvt8(x, xb, i);
  for (int i = t0; i < 1572864; i += stride) cvt8(wq, wqb, i);
  for (int i = t0; i < 524288; i += stride) cvt8(wo, wob, i);
}

// --------------------------------------------------- 128x128 bf16 GEMM core (B^T)
// R1's measured-best core: single-buffered, stage -> sync -> compute -> sync.
__device__ __forceinline__ void gemm128_core(const unsigned short* __restrict__ A,
                                             const unsigned short* __restrict__ Bt,
                                             int K, int brow, int bcol,
                                             unsigned short* lds_a, unsigned short* lds_b,
                                             f32x4 acc[4][4]) {
  const int tid = threadIdx.x;
  const int l   = tid & 63;
  const int w   = tid >> 6;
  const int wr  = (w >> 1) << 6;
  const int wc  = (w & 1) << 6;

  const int srow = tid >> 2;                       // staging row within 64-row chunk
  const int sswz = (tid & 3) ^ ((srow >> 1) & 3);  // swizzled 16B granule
  const unsigned short* gA0 = A  + (size_t)(brow + srow) * K + 8 * sswz;
  const unsigned short* gA1 = gA0 + (size_t)64 * K;
  const unsigned short* gB0 = Bt + (size_t)(bcol + srow) * K + 8 * sswz;
  const unsigned short* gB1 = gB0 + (size_t)64 * K;

  unsigned short* la0 = lds_a + tid * 8;
  unsigned short* la1 = lds_a + (256 + tid) * 8;
  unsigned short* lb0 = lds_b + tid * 8;
  unsigned short* lb1 = lds_b + (256 + tid) * 8;

  const int fm    = l & 15;
  const int fswz8 = 8 * ((l >> 4) ^ ((fm >> 1) & 3));

  for (int k0 = 0; k0 < K; k0 += 32) {
    gld_lds16(gA0, la0);
    gld_lds16(gA1, la1);
    gld_lds16(gB0, lb0);
    gld_lds16(gB1, lb1);
    gA0 += 32; gA1 += 32; gB0 += 32; gB1 += 32;
    __syncthreads();  // drains vmcnt(0): staged data visible
    bf16x8 af[4], bfv[4];
#pragma unroll
    for (int i = 0; i < 4; i++)
      af[i] = *(const bf16x8*)&lds_a[(wr + i * 16 + fm) * 32 + fswz8];
#pragma unroll
    for (int j = 0; j < 4; j++)
      bfv[j] = *(const bf16x8*)&lds_b[(wc + j * 16 + fm) * 32 + fswz8];
#pragma unroll
    for (int i = 0; i < 4; i++)
#pragma unroll
      for (int j = 0; j < 4; j++)
        acc[i][j] = MFMA16(af[i], bfv[j], acc[i][j]);
    __syncthreads();
  }
}

// --------------------------------------------------------------- QKV projection
__global__ __launch_bounds__(256) void gemm_qkv(const unsigned short* __restrict__ xb,
                                                const unsigned short* __restrict__ wqb,
                                                unsigned short* __restrict__ Qb,
                                                unsigned short* __restrict__ Kb,
                                                unsigned short* __restrict__ Vtb) {
  __shared__ alignas(16) unsigned short lds_a[128 * 32];
  __shared__ alignas(16) unsigned short lds_b[128 * 32];
  f32x4 acc[4][4];
#pragma unroll
  for (int i = 0; i < 4; i++)
#pragma unroll
    for (int j = 0; j < 4; j++) acc[i][j] = (f32x4){0.f, 0.f, 0.f, 0.f};

  const int brow = blockIdx.y << 7;
  const int bcol = blockIdx.x << 7;
  gemm128_core(xb, wqb, 2048, brow, bcol, lds_a, lds_b, acc);

  const int l = threadIdx.x & 63;
  const int w = threadIdx.x >> 6;
  const int wr = (w >> 1) << 6, wc = (w & 1) << 6;
  const int which = bcol >> 11;                         // 0=Q 1=K 2=V (block-uniform)
  const int bh = ((brow >> 11) << 4) | ((bcol >> 7) & 15);
  const int tbase = (brow & 2047) + wr + ((l >> 4) << 2);

#pragma unroll
  for (int i = 0; i < 4; i++) {
    const int t0 = tbase + i * 16;
#pragma unroll
    for (int j = 0; j < 4; j++) {
      const int d = wc + j * 16 + (l & 15);
      if (which == 2) {
        u16x4 pk;
#pragma unroll
        for (int r = 0; r < 4; r++) pk[r] = f2bf(acc[i][j][r]);
        *reinterpret_cast<u16x4*>(&Vtb[((size_t)bh * 128 + d) * 2048 + t0]) = pk;
      } else {
        unsigned short* dst = (which == 0 ? Qb : Kb) + ((size_t)bh * 2048 + t0) * 128 + d;
#pragma unroll
        for (int r = 0; r < 4; r++) dst[(size_t)r * 128] = f2bf(acc[i][j][r]);
      }
    }
  }
}

// -------------------------------------------------------------- output projection
__global__ __launch_bounds__(256) void gemm_out(const unsigned short* __restrict__ yb,
                                                const unsigned short* __restrict__ wob,
                                                float* __restrict__ out) {
  __shared__ alignas(16) unsigned short lds_a[128 * 32];
  __shared__ alignas(16) unsigned short lds_b[128 * 32];
  f32x4 acc[4][4];
#pragma unroll
  for (int i = 0; i < 4; i++)
#pragma unroll
    for (int j = 0; j < 4; j++) acc[i][j] = (f32x4){0.f, 0.f, 0.f, 0.f};

  const int brow = blockIdx.y << 7;
  const int bcol = blockIdx.x << 7;
  gemm128_core(yb, wob, 2048, brow, bcol, lds_a, lds_b, acc);

  const int l = threadIdx.x & 63;
  const int w = threadIdx.x >> 6;
  const int wr = (w >> 1) << 6, wc = (w & 1) << 6;
#pragma unroll
  for (int i = 0; i < 4; i++) {
    const int m0 = brow + wr + i * 16 + ((l >> 4) << 2);
#pragma unroll
    for (int j = 0; j < 4; j++) {
      const int n = bcol + wc + j * 16 + (l & 15);
#pragma unroll
      for (int r = 0; r < 4; r++) out[(size_t)(m0 + r) * 2048 + n] = acc[i][j][r];
    }
  }
}

// ------------------------------------------------------------------ flash attn
// 8-WAVE SPLIT of the causal pair: waves 0-3 own tile j's 64 rows, waves 4-7
// own tile 31-j.  Per kv-step each wave runs ONE tile-step (was two serial)
// -> serial chain halves, active waves/SIMD 2 -> up to 4.  Work per block
// constant (132 wave-tile-steps).  K,V double-buffered; one vmcnt(0)+barrier
// per kv-step.  Defer-max + deferred sum (R9).  LDS 80 KiB -> 2 blocks/CU;
// launch_bounds(512,4) caps VGPR at 128 for 4 waves/SIMD.
// Complementary jidx remap: co-resident blocks (bid, bid+256) get lengths
// summing to 49 steps -> per-CU wave-work uniform.
__device__ __forceinline__ void stage_kv64(const unsigned short* __restrict__ Kg,
                                           const unsigned short* __restrict__ Vg,
                                           int kv0, unsigned short* dk,
                                           unsigned short* dv, int tid) {
#pragma unroll
  for (int c = 0; c < 2; c++) {
    int s = c * 512 + tid;
    int row = s >> 4, g = s & 15;
    gld_lds16(&Kg[(size_t)(kv0 + row) * 128 + 8 * (g ^ (row & 7))], &dk[s * 8]);
  }
#pragma unroll
  for (int c = 0; c < 2; c++) {
    int s = c * 512 + tid;
    int row = s >> 3, g = s & 7;
    gld_lds16(&Vg[(size_t)row * 2048 + kv0 + 8 * (g ^ (row & 7))], &dv[s * 8]);
  }
}

// one q-tile's contribution for one kv-tile (QK^T -> online softmax -> PV)
__device__ __forceinline__ void attn_tile_step(const bf16x8 qf[4], f32x4 yacc[8],
                                               float mrow[4], float lsum[4],
                                               int qw0, int kv0,
                                               const unsigned short* kb,
                                               const unsigned short* vb,
                                               unsigned short* pw, int l) {
  const float SC = 0.12752585f;  // log2(e)/sqrt(128)
  // S = Q K^T : 16 MFMA
  f32x4 sfr[4];
  __builtin_amdgcn_s_setprio(1);
#pragma unroll
  for (int kt = 0; kt < 4; kt++) {
    const int kr = kt * 16 + (l & 15);
    f32x4 s4 = (f32x4){0.f, 0.f, 0.f, 0.f};
#pragma unroll
    for (int ds = 0; ds < 4; ds++) {
      bf16x8 kfr = *(const bf16x8*)&kb[kr * 128 + 8 * (((ds << 2) + (l >> 4)) ^ (kr & 7))];
      s4 = MFMA16(qf[ds], kfr, s4);
    }
    sfr[kt] = s4;
  }
  __builtin_amdgcn_s_setprio(0);
  const bool need_mask = (kv0 + 63 > qw0);
#pragma unroll
  for (int kt = 0; kt < 4; kt++)
#pragma unroll
    for (int r = 0; r < 4; r++) {
      float sv = sfr[kt][r] * SC;
      if (need_mask) {
        int qa = qw0 + ((l >> 4) << 2) + r;
        int ka = kv0 + kt * 16 + (l & 15);
        sv = (ka > qa) ? -1e30f : sv;
      }
      sfr[kt][r] = sv;
    }
  // per-lane partial row max (rows at (l>>4)*4 + r, cols on l&15)
  float prmax[4];
#pragma unroll
  for (int r = 0; r < 4; r++)
    prmax[r] = fmaxf(fmaxf(sfr[0][r], sfr[1][r]), fmaxf(sfr[2][r], sfr[3][r]));
  // T13 defer-max, cheap per-lane check: skip shfl reduce AND rescale usually
  bool sm = (prmax[0] <= mrow[0] + 8.f) && (prmax[1] <= mrow[1] + 8.f) &&
            (prmax[2] <= mrow[2] + 8.f) && (prmax[3] <= mrow[3] + 8.f);
  if (!__all(sm)) {
    float f[4];
#pragma unroll
    for (int r = 0; r < 4; r++) {
      float m = prmax[r];
      m = fmaxf(m, __shfl_xor(m, 1));
      m = fmaxf(m, __shfl_xor(m, 2));
      m = fmaxf(m, __shfl_xor(m, 4));
      m = fmaxf(m, __shfl_xor(m, 8));
      float mn = fmaxf(mrow[r], m);
      f[r] = exp2f(mrow[r] - mn);   // row-uniform across the 16 lanes of a row
      mrow[r] = mn;
      lsum[r] *= f[r];
    }
#pragma unroll
    for (int dt = 0; dt < 8; dt++)
#pragma unroll
      for (int r = 0; r < 4; r++) yacc[dt][r] *= f[r];
  }
  // P = exp2(S - m) (bounded by 2^8 when deferred); per-lane deferred sum
#pragma unroll
  for (int kt = 0; kt < 4; kt++)
#pragma unroll
    for (int r = 0; r < 4; r++) {
      float p = exp2f(sfr[kt][r] - mrow[r]);
      lsum[r] += p;
      int row = ((l >> 4) << 2) + r;
      int k = kt * 16 + (l & 15);
      pw[row * 64 + (((k >> 3) ^ (row & 7)) << 3) + (k & 7)] = f2bf(p);
    }
  // cross-lane LDS write->read fence (same wave); rule #18 sched_barrier
  asm volatile("s_waitcnt lgkmcnt(0)" ::: "memory");
  __builtin_amdgcn_sched_barrier(0);
  // PV: 16 MFMA.  A = P, B = V from V^T LDS
  __builtin_amdgcn_s_setprio(1);
#pragma unroll
  for (int ks = 0; ks < 2; ks++) {
    const int prow = l & 15;
    bf16x8 pa = *(const bf16x8*)&pw[prow * 64 + ((((ks << 2) + (l >> 4)) ^ (prow & 7)) << 3)];
#pragma unroll
    for (int dt = 0; dt < 8; dt++) {
      const int d = dt * 16 + (l & 15);
      bf16x8 vv = *(const bf16x8*)&vb[d * 64 + ((((ks << 2) + (l >> 4)) ^ (d & 7)) << 3)];
      yacc[dt] = MFMA16(pa, vv, yacc[dt]);
    }
  }
  __builtin_amdgcn_s_setprio(0);
}

__global__ __launch_bounds__(512, 4) void attn_kernel(const unsigned short* __restrict__ Qb,
                                                      const unsigned short* __restrict__ Kb,
                                                      const unsigned short* __restrict__ Vtb,
                                                      unsigned short* __restrict__ Yb) {
  __shared__ alignas(16) unsigned short lds_k[2][64 * 128];
  __shared__ alignas(16) unsigned short lds_v[2][128 * 64];
  __shared__ alignas(16) unsigned short p_lds[8][16 * 64];  // one per wave

  const int tid = threadIdx.x;
  const int l = tid & 63;
  const int w = tid >> 6;                    // 0..7

  const int bid = blockIdx.x;                // 0..511
  const int xcd = bid & 7;
  const int loc = bid >> 3;                  // 0..63
  const int bh = xcd * 4 + (loc >> 4);       // 0..31 (XCD-grouped KV)
  // complementary length pairing: loc and loc+32 get jidx j and 15-j
  const int jraw = loc & 15;
  const int jidx = (loc < 32) ? jraw : (15 - jraw);

  const int b = bh >> 4, h = bh & 15;

  const unsigned short* Qg = Qb + (size_t)bh * 2048 * 128;
  const unsigned short* Kg = Kb + (size_t)bh * 2048 * 128;
  const unsigned short* Vg = Vtb + (size_t)bh * 128 * 2048;

  // waves 0-3: tile jidx (rows (w&3)*16); waves 4-7: tile 31-jidx
  const int my_j = (w < 4) ? jidx : (31 - jidx);
  const int qw0 = (my_j << 6) + ((w & 3) << 4);

  // Q fragments (A-operand: m = l&15, k = ds*32 + 8*(l>>4))
  bf16x8 qf[4];
#pragma unroll
  for (int ds = 0; ds < 4; ds++)
    qf[ds] = *(const bf16x8*)&Qg[(size_t)(qw0 + (l & 15)) * 128 + ds * 32 + 8 * (l >> 4)];

  f32x4 yacc[8];
#pragma unroll
  for (int dt = 0; dt < 8; dt++) yacc[dt] = (f32x4){0.f, 0.f, 0.f, 0.f};
  float mrow[4], lsum[4];
#pragma unroll
  for (int r = 0; r < 4; r++) { mrow[r] = -1e30f; lsum[r] = 0.f; }

  const int nkv = (31 - jidx) + 1;  // hi tile bound: 17..32 kv-steps

  // prologue: stage tile 0
  stage_kv64(Kg, Vg, 0, lds_k[0], lds_v[0], tid);
  asm volatile("s_waitcnt vmcnt(0)" ::: "memory");
  __syncthreads();

  for (int t = 0; t < nkv; t++) {
    const int kv0 = t << 6;
    const int buf = t & 1;
    if (t + 1 < nkv)
      stage_kv64(Kg, Vg, kv0 + 64, lds_k[buf ^ 1], lds_v[buf ^ 1], tid);

    // hi waves: always active; lo waves: active while kv0 <= qw0+15
    if (kv0 <= qw0 + 15)
      attn_tile_step(qf, yacc, mrow, lsum, qw0, kv0, lds_k[buf], lds_v[buf],
                     p_lds[w], l);

    asm volatile("s_waitcnt vmcnt(0)" ::: "memory");
    __syncthreads();
  }

  // epilogue: reduce deferred sum once, then y = acc / l into [B,T,C]
  float lrow[4];
#pragma unroll
  for (int r = 0; r < 4; r++) {
    float s = lsum[r];
    s += __shfl_xor(s, 1); s += __shfl_xor(s, 2);
    s += __shfl_xor(s, 4); s += __shfl_xor(s, 8);
    lrow[r] = s;
  }
#pragma unroll
  for (int dt = 0; dt < 8; dt++)
#pragma unroll
    for (int r = 0; r < 4; r++) {
      int qa = qw0 + ((l >> 4) << 2) + r;
      Yb[((size_t)(b * 2048 + qa)) * 2048 + h * 128 + dt * 16 + (l & 15)] =
          f2bf(yacc[dt][r] / lrow[r]);
    }
}

// ---------------------------------------------------------------------- launch
extern "C" void kernel_launch(void* const* d_in, const int* in_sizes, int n_in,
                              void* d_out, int out_size, void* d_ws, size_t ws_size,
                              hipStream_t stream) {
  const float* x    = (const float*)d_in[0];
  const float* wqkv = (const float*)d_in[1];
  const float* wout = (const float*)d_in[2];
  float* out = (float*)d_out;

  // workspace layout (bf16 elements)
  unsigned short* ws  = (unsigned short*)d_ws;
  unsigned short* xb  = ws;                        // 4096*2048
  unsigned short* wqb = xb + (size_t)8388608;      // 6144*2048
  unsigned short* wob = wqb + (size_t)12582912;    // 2048*2048
  unsigned short* Qb  = wob + (size_t)4194304;     // [32,2048,128]
  unsigned short* Kb  = Qb + (size_t)8388608;      // [32,2048,128]
  unsigned short* Vtb = Kb + (size_t)8388608;      // [32,128,2048] (transposed)
  unsigned short* Yb  = Vtb + (size_t)8388608;     // [4096,2048]

  cvt_all<<<2048, 256, 0, stream>>>(x, wqkv, wout, xb, wqb, wob);
  gemm_qkv<<<dim3(48, 32), 256, 0, stream>>>(xb, wqb, Qb, Kb, Vtb);
  attn_kernel<<<512, 512, 0, stream>>>(Qb, Kb, Vtb, Yb);
  gemm_out<<<dim3(16, 32), 256, 0, stream>>>(Yb, wob, out);
}

// Round 11
// 246.398 us; speedup vs baseline: 1.6270x; 1.0647x over previous
//
#include <hip/hip_runtime.h>
#include <stdint.h>

// SoftmaxAttention: x[2,2048,2048] f32, w_qkv[6144,2048] f32, w_out[2048,2048] f32
// out[2,2048,2048] f32.  All matmul-shaped compute via bf16 MFMA 16x16x32.

typedef __attribute__((ext_vector_type(8))) short bf16x8;
typedef __attribute__((ext_vector_type(8))) unsigned short u16x8;
typedef __attribute__((ext_vector_type(4))) unsigned short u16x4;
typedef __attribute__((ext_vector_type(4))) float f32x4;

#define MFMA16(a, b, c) __builtin_amdgcn_mfma_f32_16x16x32_bf16((a), (b), (c), 0, 0, 0)

__device__ __forceinline__ unsigned short f2bf(float f) {
  union { float f; uint32_t u; } v; v.f = f;
  uint32_t r = v.u + 0x7FFFu + ((v.u >> 16) & 1u);  // RNE
  return (unsigned short)(r >> 16);
}

__device__ __forceinline__ void gld_lds16(const unsigned short* g, unsigned short* lds) {
  __builtin_amdgcn_global_load_lds(
      (const __attribute__((address_space(1))) void*)g,
      (__attribute__((address_space(3))) void*)lds, 16, 0, 0);
}

// ---------------------------------------------------------------- cvt f32->bf16
__device__ __forceinline__ void cvt8(const float* __restrict__ in,
                                     unsigned short* __restrict__ out, int i) {
  float4 a = reinterpret_cast<const float4*>(in)[i * 2];
  float4 b = reinterpret_cast<const float4*>(in)[i * 2 + 1];
  u16x8 o;
  o[0] = f2bf(a.x); o[1] = f2bf(a.y); o[2] = f2bf(a.z); o[3] = f2bf(a.w);
  o[4] = f2bf(b.x); o[5] = f2bf(b.y); o[6] = f2bf(b.z); o[7] = f2bf(b.w);
  reinterpret_cast<u16x8*>(out)[i] = o;
}

__global__ __launch_bounds__(256) void cvt_all(const float* __restrict__ x,
                                               const float* __restrict__ wq,
                                               const float* __restrict__ wo,
                                               unsigned short* __restrict__ xb,
                                               unsigned short* __restrict__ wqb,
                                               unsigned short* __restrict__ wob) {
  const int stride = gridDim.x * blockDim.x;
  const int t0 = blockIdx.x * blockDim.x + threadIdx.x;
  for (int i = t0; i < 1048576; i += stride) cvt8(x, xb, i);
  for (int i = t0; i < 1572864; i += stride) cvt8(wq, wqb, i);
  for (int i = t0; i < 524288; i += stride) cvt8(wo, wob, i);
}

// ============== 128x128 bf16 GEMM core, BK=64 single-buffer (B^T) =============
// C[m][n] = sum_k A[m][k]*Bt[n][k].  256 thr, 4 waves (2x2 of 64x64).
// Per K-step(64): 8 gld_lds + barrier + (8 ds_read + 16 MFMA) x2 + barrier
// -- half the barriers of BK=32 per FLOP.  LDS tiles [128][64] (16 KiB each).
// T2 swizzle for 128B row stride: granule g_lds = g_global ^ (row&7), applied
// as pre-swizzled global source (rule #21) + XOR'd fragment read.  Per
// quarter-wave each bank-group serves exactly 2 lanes -> conflict-free.
__device__ __forceinline__ void gemm128_core(const unsigned short* __restrict__ A,
                                             const unsigned short* __restrict__ Bt,
                                             int K, int brow, int bcol,
                                             unsigned short* lds_a, unsigned short* lds_b,
                                             f32x4 acc[4][4]) {
  const int tid = threadIdx.x;
  const int l   = tid & 63;
  const int w   = tid >> 6;
  const int wr  = (w >> 1) << 6;
  const int wc  = (w & 1) << 6;

  // staging: slot s = c*256+tid, row = s>>3 = c*32 + (tid>>3), g_lds = tid&7,
  // g_src = g_lds ^ (row&7)  (row&7 is c-independent since 32%8==0)
  const int srow = tid >> 3;
  const int gsrc = (tid & 7) ^ (srow & 7);
  const unsigned short* gA0 = A  + (size_t)(brow + srow) * K + 8 * gsrc;
  const unsigned short* gB0 = Bt + (size_t)(bcol + srow) * K + 8 * gsrc;
  unsigned short* dA0 = lds_a + tid * 8;
  unsigned short* dB0 = lds_b + tid * 8;

  const int fm = l & 15;
  const int q  = l >> 4;

  for (int k0 = 0; k0 < K; k0 += 64) {
#pragma unroll
    for (int c = 0; c < 4; c++)
      gld_lds16(gA0 + (size_t)c * 32 * K + k0, dA0 + c * 2048);
#pragma unroll
    for (int c = 0; c < 4; c++)
      gld_lds16(gB0 + (size_t)c * 32 * K + k0, dB0 + c * 2048);
    __syncthreads();  // drains vmcnt(0): staged data visible
#pragma unroll
    for (int ks = 0; ks < 2; ks++) {
      const int goff = 8 * ((ks * 4 + q) ^ (fm & 7));
      bf16x8 af[4], bfv[4];
#pragma unroll
      for (int i = 0; i < 4; i++)
        af[i] = *(const bf16x8*)&lds_a[(wr + i * 16 + fm) * 64 + goff];
#pragma unroll
      for (int j = 0; j < 4; j++)
        bfv[j] = *(const bf16x8*)&lds_b[(wc + j * 16 + fm) * 64 + goff];
#pragma unroll
      for (int i = 0; i < 4; i++)
#pragma unroll
        for (int j = 0; j < 4; j++)
          acc[i][j] = MFMA16(af[i], bfv[j], acc[i][j]);
    }
    __syncthreads();
  }
}

// --------------------------------------------------------------- QKV projection
// Epilogue folds softmax scale log2(e)/sqrt(128) into Q (which==0) so attn's
// per-step scale multiply disappears.
__global__ __launch_bounds__(256) void gemm_qkv(const unsigned short* __restrict__ xb,
                                                const unsigned short* __restrict__ wqb,
                                                unsigned short* __restrict__ Qb,
                                                unsigned short* __restrict__ Kb,
                                                unsigned short* __restrict__ Vtb) {
  __shared__ alignas(16) unsigned short lds_a[128 * 64];
  __shared__ alignas(16) unsigned short lds_b[128 * 64];
  f32x4 acc[4][4];
#pragma unroll
  for (int i = 0; i < 4; i++)
#pragma unroll
    for (int j = 0; j < 4; j++) acc[i][j] = (f32x4){0.f, 0.f, 0.f, 0.f};

  const int brow = blockIdx.y << 7;
  const int bcol = blockIdx.x << 7;
  gemm128_core(xb, wqb, 2048, brow, bcol, lds_a, lds_b, acc);

  const int l = threadIdx.x & 63;
  const int w = threadIdx.x >> 6;
  const int wr = (w >> 1) << 6, wc = (w & 1) << 6;
  const int which = bcol >> 11;                         // 0=Q 1=K 2=V (block-uniform)
  const float qs = (which == 0) ? 0.12752585f : 1.0f;   // log2(e)/sqrt(128) into Q
  const int bh = ((brow >> 11) << 4) | ((bcol >> 7) & 15);
  const int tbase = (brow & 2047) + wr + ((l >> 4) << 2);

#pragma unroll
  for (int i = 0; i < 4; i++) {
    const int t0 = tbase + i * 16;
#pragma unroll
    for (int j = 0; j < 4; j++) {
      const int d = wc + j * 16 + (l & 15);
      if (which == 2) {
        u16x4 pk;
#pragma unroll
        for (int r = 0; r < 4; r++) pk[r] = f2bf(acc[i][j][r]);
        *reinterpret_cast<u16x4*>(&Vtb[((size_t)bh * 128 + d) * 2048 + t0]) = pk;
      } else {
        unsigned short* dst = (which == 0 ? Qb : Kb) + ((size_t)bh * 2048 + t0) * 128 + d;
#pragma unroll
        for (int r = 0; r < 4; r++) dst[(size_t)r * 128] = f2bf(acc[i][j][r] * qs);
      }
    }
  }
}

// -------------------------------------------------------------- output projection
__global__ __launch_bounds__(256) void gemm_out(const unsigned short* __restrict__ yb,
                                                const unsigned short* __restrict__ wob,
                                                float* __restrict__ out) {
  __shared__ alignas(16) unsigned short lds_a[128 * 64];
  __shared__ alignas(16) unsigned short lds_b[128 * 64];
  f32x4 acc[4][4];
#pragma unroll
  for (int i = 0; i < 4; i++)
#pragma unroll
    for (int j = 0; j < 4; j++) acc[i][j] = (f32x4){0.f, 0.f, 0.f, 0.f};

  const int brow = blockIdx.y << 7;
  const int bcol = blockIdx.x << 7;
  gemm128_core(yb, wob, 2048, brow, bcol, lds_a, lds_b, acc);

  const int l = threadIdx.x & 63;
  const int w = threadIdx.x >> 6;
  const int wr = (w >> 1) << 6, wc = (w & 1) << 6;
#pragma unroll
  for (int i = 0; i < 4; i++) {
    const int m0 = brow + wr + i * 16 + ((l >> 4) << 2);
#pragma unroll
    for (int j = 0; j < 4; j++) {
      const int n = bcol + wc + j * 16 + (l & 15);
#pragma unroll
      for (int r = 0; r < 4; r++) out[(size_t)(m0 + r) * 2048 + n] = acc[i][j][r];
    }
  }
}

// ------------------------------------------------------------------ flash attn
// 8-wave split of the causal pair (R10 structure).  This round: Q pre-scaled
// in gemm_qkv (no per-step SC multiply) and P stored via TRUNCATION (1 op)
// instead of 4-op RNE -- P in [0,2^8], bias ~0.2%, inside threshold.
__device__ __forceinline__ void stage_kv64(const unsigned short* __restrict__ Kg,
                                           const unsigned short* __restrict__ Vg,
                                           int kv0, unsigned short* dk,
                                           unsigned short* dv, int tid) {
#pragma unroll
  for (int c = 0; c < 2; c++) {
    int s = c * 512 + tid;
    int row = s >> 4, g = s & 15;
    gld_lds16(&Kg[(size_t)(kv0 + row) * 128 + 8 * (g ^ (row & 7))], &dk[s * 8]);
  }
#pragma unroll
  for (int c = 0; c < 2; c++) {
    int s = c * 512 + tid;
    int row = s >> 3, g = s & 7;
    gld_lds16(&Vg[(size_t)row * 2048 + kv0 + 8 * (g ^ (row & 7))], &dv[s * 8]);
  }
}

// one q-tile's contribution for one kv-tile (QK^T -> online softmax -> PV)
__device__ __forceinline__ void attn_tile_step(const bf16x8 qf[4], f32x4 yacc[8],
                                               float mrow[4], float lsum[4],
                                               int qw0, int kv0,
                                               const unsigned short* kb,
                                               const unsigned short* vb,
                                               unsigned short* pw, int l) {
  // S = Q K^T : 16 MFMA (Q pre-scaled by log2(e)/sqrt(128))
  f32x4 sfr[4];
  __builtin_amdgcn_s_setprio(1);
#pragma unroll
  for (int kt = 0; kt < 4; kt++) {
    const int kr = kt * 16 + (l & 15);
    f32x4 s4 = (f32x4){0.f, 0.f, 0.f, 0.f};
#pragma unroll
    for (int ds = 0; ds < 4; ds++) {
      bf16x8 kfr = *(const bf16x8*)&kb[kr * 128 + 8 * (((ds << 2) + (l >> 4)) ^ (kr & 7))];
      s4 = MFMA16(qf[ds], kfr, s4);
    }
    sfr[kt] = s4;
  }
  __builtin_amdgcn_s_setprio(0);
  const bool need_mask = (kv0 + 63 > qw0);
  if (need_mask) {
#pragma unroll
    for (int kt = 0; kt < 4; kt++)
#pragma unroll
      for (int r = 0; r < 4; r++) {
        int qa = qw0 + ((l >> 4) << 2) + r;
        int ka = kv0 + kt * 16 + (l & 15);
        if (ka > qa) sfr[kt][r] = -1e30f;
      }
  }
  // per-lane partial row max (rows at (l>>4)*4 + r, cols on l&15)
  float prmax[4];
#pragma unroll
  for (int r = 0; r < 4; r++)
    prmax[r] = fmaxf(fmaxf(sfr[0][r], sfr[1][r]), fmaxf(sfr[2][r], sfr[3][r]));
  // T13 defer-max, cheap per-lane check: skip shfl reduce AND rescale usually
  bool sm = (prmax[0] <= mrow[0] + 8.f) && (prmax[1] <= mrow[1] + 8.f) &&
            (prmax[2] <= mrow[2] + 8.f) && (prmax[3] <= mrow[3] + 8.f);
  if (!__all(sm)) {
    float f[4];
#pragma unroll
    for (int r = 0; r < 4; r++) {
      float m = prmax[r];
      m = fmaxf(m, __shfl_xor(m, 1));
      m = fmaxf(m, __shfl_xor(m, 2));
      m = fmaxf(m, __shfl_xor(m, 4));
      m = fmaxf(m, __shfl_xor(m, 8));
      float mn = fmaxf(mrow[r], m);
      f[r] = exp2f(mrow[r] - mn);   // row-uniform across the 16 lanes of a row
      mrow[r] = mn;
      lsum[r] *= f[r];
    }
#pragma unroll
    for (int dt = 0; dt < 8; dt++)
#pragma unroll
      for (int r = 0; r < 4; r++) yacc[dt][r] *= f[r];
  }
  // P = exp2(S - m) (bounded by 2^8 when deferred); per-lane deferred sum;
  // bf16 by truncation (P >= 0, bias ~2^-9 -- cheap and in-budget)
#pragma unroll
  for (int kt = 0; kt < 4; kt++)
#pragma unroll
    for (int r = 0; r < 4; r++) {
      float p = exp2f(sfr[kt][r] - mrow[r]);
      lsum[r] += p;
      union { float f; uint32_t u; } cc; cc.f = p;
      int row = ((l >> 4) << 2) + r;
      int k = kt * 16 + (l & 15);
      pw[row * 64 + (((k >> 3) ^ (row & 7)) << 3) + (k & 7)] =
          (unsigned short)(cc.u >> 16);
    }
  // cross-lane LDS write->read fence (same wave); rule #18 sched_barrier
  asm volatile("s_waitcnt lgkmcnt(0)" ::: "memory");
  __builtin_amdgcn_sched_barrier(0);
  // PV: 16 MFMA.  A = P, B = V from V^T LDS
  __builtin_amdgcn_s_setprio(1);
#pragma unroll
  for (int ks = 0; ks < 2; ks++) {
    const int prow = l & 15;
    bf16x8 pa = *(const bf16x8*)&pw[prow * 64 + ((((ks << 2) + (l >> 4)) ^ (prow & 7)) << 3)];
#pragma unroll
    for (int dt = 0; dt < 8; dt++) {
      const int d = dt * 16 + (l & 15);
      bf16x8 vv = *(const bf16x8*)&vb[d * 64 + ((((ks << 2) + (l >> 4)) ^ (d & 7)) << 3)];
      yacc[dt] = MFMA16(pa, vv, yacc[dt]);
    }
  }
  __builtin_amdgcn_s_setprio(0);
}

__global__ __launch_bounds__(512, 4) void attn_kernel(const unsigned short* __restrict__ Qb,
                                                      const unsigned short* __restrict__ Kb,
                                                      const unsigned short* __restrict__ Vtb,
                                                      unsigned short* __restrict__ Yb) {
  __shared__ alignas(16) unsigned short lds_k[2][64 * 128];
  __shared__ alignas(16) unsigned short lds_v[2][128 * 64];
  __shared__ alignas(16) unsigned short p_lds[8][16 * 64];  // one per wave

  const int tid = threadIdx.x;
  const int l = tid & 63;
  const int w = tid >> 6;                    // 0..7

  const int bid = blockIdx.x;                // 0..511
  const int xcd = bid & 7;
  const int loc = bid >> 3;                  // 0..63
  const int bh = xcd * 4 + (loc >> 4);       // 0..31 (XCD-grouped KV)
  // complementary length pairing: loc and loc+32 get jidx j and 15-j
  const int jraw = loc & 15;
  const int jidx = (loc < 32) ? jraw : (15 - jraw);

  const int b = bh >> 4, h = bh & 15;

  const unsigned short* Qg = Qb + (size_t)bh * 2048 * 128;
  const unsigned short* Kg = Kb + (size_t)bh * 2048 * 128;
  const unsigned short* Vg = Vtb + (size_t)bh * 128 * 2048;

  // waves 0-3: tile jidx (rows (w&3)*16); waves 4-7: tile 31-jidx
  const int my_j = (w < 4) ? jidx : (31 - jidx);
  const int qw0 = (my_j << 6) + ((w & 3) << 4);

  // Q fragments (A-operand: m = l&15, k = ds*32 + 8*(l>>4))
  bf16x8 qf[4];
#pragma unroll
  for (int ds = 0; ds < 4; ds++)
    qf[ds] = *(const bf16x8*)&Qg[(size_t)(qw0 + (l & 15)) * 128 + ds * 32 + 8 * (l >> 4)];

  f32x4 yacc[8];
#pragma unroll
  for (int dt = 0; dt < 8; dt++) yacc[dt] = (f32x4){0.f, 0.f, 0.f, 0.f};
  float mrow[4], lsum[4];
#pragma unroll
  for (int r = 0; r < 4; r++) { mrow[r] = -1e30f; lsum[r] = 0.f; }

  const int nkv = (31 - jidx) + 1;  // hi tile bound: 17..32 kv-steps

  // prologue: stage tile 0
  stage_kv64(Kg, Vg, 0, lds_k[0], lds_v[0], tid);
  asm volatile("s_waitcnt vmcnt(0)" ::: "memory");
  __syncthreads();

  for (int t = 0; t < nkv; t++) {
    const int kv0 = t << 6;
    const int buf = t & 1;
    if (t + 1 < nkv)
      stage_kv64(Kg, Vg, kv0 + 64, lds_k[buf ^ 1], lds_v[buf ^ 1], tid);

    // hi waves: always active; lo waves: active while kv0 <= qw0+15
    if (kv0 <= qw0 + 15)
      attn_tile_step(qf, yacc, mrow, lsum, qw0, kv0, lds_k[buf], lds_v[buf],
                     p_lds[w], l);

    asm volatile("s_waitcnt vmcnt(0)" ::: "memory");
    __syncthreads();
  }

  // epilogue: reduce deferred sum once, then y = acc / l into [B,T,C]
  float lrow[4];
#pragma unroll
  for (int r = 0; r < 4; r++) {
    float s = lsum[r];
    s += __shfl_xor(s, 1); s += __shfl_xor(s, 2);
    s += __shfl_xor(s, 4); s += __shfl_xor(s, 8);
    lrow[r] = s;
  }
#pragma unroll
  for (int dt = 0; dt < 8; dt++)
#pragma unroll
    for (int r = 0; r < 4; r++) {
      int qa = qw0 + ((l >> 4) << 2) + r;
      Yb[((size_t)(b * 2048 + qa)) * 2048 + h * 128 + dt * 16 + (l & 15)] =
          f2bf(yacc[dt][r] / lrow[r]);
    }
}

// ---------------------------------------------------------------------- launch
extern "C" void kernel_launch(void* const* d_in, const int* in_sizes, int n_in,
                              void* d_out, int out_size, void* d_ws, size_t ws_size,
                              hipStream_t stream) {
  const float* x    = (const float*)d_in[0];
  const float* wqkv = (const float*)d_in[1];
  const float* wout = (const float*)d_in[2];
  float* out = (float*)d_out;

  // workspace layout (bf16 elements)
  unsigned short* ws  = (unsigned short*)d_ws;
  unsigned short* xb  = ws;                        // 4096*2048
  unsigned short* wqb = xb + (size_t)8388608;      // 6144*2048
  unsigned short* wob = wqb + (size_t)12582912;    // 2048*2048
  unsigned short* Qb  = wob + (size_t)4194304;     // [32,2048,128] (pre-scaled)
  unsigned short* Kb  = Qb + (size_t)8388608;      // [32,2048,128]
  unsigned short* Vtb = Kb + (size_t)8388608;      // [32,128,2048] (transposed)
  unsigned short* Yb  = Vtb + (size_t)8388608;     // [4096,2048]

  cvt_all<<<2048, 256, 0, stream>>>(x, wqkv, wout, xb, wqb, wob);
  gemm_qkv<<<dim3(48, 32), 256, 0, stream>>>(xb, wqb, Qb, Kb, Vtb);
  attn_kernel<<<512, 512, 0, stream>>>(Qb, Kb, Vtb, Yb);
  gemm_out<<<dim3(16, 32), 256, 0, stream>>>(Yb, wob, out);
}